// Round 13
// baseline (388.571 us; speedup 1.0000x reference)
//
#include <hip/hip_runtime.h>
#include <hip/hip_bf16.h>
#include <hip/hip_cooperative_groups.h>

namespace cg = cooperative_groups;

#define TT 128
#define BB 64
#define NN 1024

typedef __attribute__((ext_vector_type(4))) float f32x4;
typedef __attribute__((ext_vector_type(8))) short bf16x8;

#define FLAG_THR 2e-4
#define MAX_FLAG 16384

// ---------------------------------------------------------------------------
// bf16 split helpers (RNE via bit trick; residual exact in fp32)
// ---------------------------------------------------------------------------
__device__ __forceinline__ unsigned short bf_hi_rne(float f, float& rem) {
    union { float f; unsigned int u; } c; c.f = f;
    const unsigned int r = c.u + 0x7fffu + ((c.u >> 16) & 1u);
    const unsigned short h = (unsigned short)(r >> 16);
    union { unsigned int u; float f; } b; b.u = ((unsigned int)h) << 16;
    rem = f - b.f;
    return h;
}

// Fused prep kernel (r11-proven), block-range dispatch:
//   [0,8192) split x; [8192,9216) split w1; [9216,10240) transpose w2.
//   block 0 thread 0 zeroes the flag counter.
__global__ __launch_bounds__(256) void split_k(const float* __restrict__ X,
                                               unsigned short* __restrict__ XHi,
                                               unsigned short* __restrict__ XLo,
                                               const float* __restrict__ W,
                                               unsigned short* __restrict__ WHi,
                                               unsigned short* __restrict__ WLo,
                                               const float* __restrict__ W2,
                                               float* __restrict__ W2T,
                                               int* __restrict__ cnt) {
    __shared__ float tile[32][33];
    if (blockIdx.x == 0 && threadIdx.x == 0) *cnt = 0;

    if (blockIdx.x >= 9216) {
        const int tblk = blockIdx.x - 9216;
        const int tx  = threadIdx.x & 31;
        const int ty4 = (threadIdx.x >> 5) * 4;
        const int c0 = (tblk & 31) * 32;
        const int r0 = (tblk >> 5) * 32;
#pragma unroll
        for (int i = 0; i < 4; ++i)
            tile[ty4 + i][tx] = W2[(size_t)(r0 + ty4 + i) * NN + c0 + tx];
        __syncthreads();
#pragma unroll
        for (int i = 0; i < 4; ++i)
            W2T[(size_t)(c0 + ty4 + i) * NN + r0 + tx] = tile[tx][ty4 + i];
        return;
    }

    const bool isX = blockIdx.x < 8192;
    const float* A = isX ? X : W;
    unsigned short* Hi = isX ? XHi : WHi;
    unsigned short* Lo = isX ? XLo : WLo;
    const size_t blk = isX ? blockIdx.x : (blockIdx.x - 8192);
    const size_t f = (blk * 256 + threadIdx.x) * 4;
    const float4 v = *(const float4*)(A + f);
    float r, r2;
    ushort4 hi, lo;
    hi.x = bf_hi_rne(v.x, r); lo.x = bf_hi_rne(r, r2);
    hi.y = bf_hi_rne(v.y, r); lo.y = bf_hi_rne(r, r2);
    hi.z = bf_hi_rne(v.z, r); lo.z = bf_hi_rne(r, r2);
    hi.w = bf_hi_rne(v.w, r); lo.w = bf_hi_rne(r, r2);
    *(ushort4*)(Hi + f) = hi;
    *(ushort4*)(Lo + f) = lo;
}

// ---------------------------------------------------------------------------
// Phase macros (shared by the cooperative mega kernel and the fallback
// standalone kernels). All reference locals declared at the expansion site.
// ---------------------------------------------------------------------------
#define STAGE(BI, KT)                                                         \
    {                                                                         \
        _Pragma("unroll")                                                     \
        for (int q = 0; q < 4; ++q) {                                         \
            const int slot = shalf + q * 64 + lane;                           \
            const int row  = slot >> 2;                                       \
            const int kc   = (slot & 3) ^ ((row >> 1) & 3);                   \
            const size_t grow = isA ? ((size_t)row * 64 + bm)                 \
                                    : ((size_t)bn * 128 + row);               \
            const unsigned short* gp =                                        \
                gsrc + grow * NN + (KT) * 32 + kc * 8;                        \
            __builtin_amdgcn_global_load_lds(                                 \
                (const __attribute__((address_space(1))) void*)gp,            \
                (__attribute__((address_space(3))) void*)(                    \
                    &ldsbuf[BI][buf][(wave & 1) * 2048 + q * 512]),           \
                16, 0, 0);                                                    \
        }                                                                     \
    }

#define COMPUTE(BI)                                                           \
    {                                                                         \
        const int c  = lane >> 4;                                             \
        const int rA = lane & 15;                                             \
        bf16x8 a0[4], a1[4], b0[2], b1[2];                                    \
        _Pragma("unroll")                                                     \
        for (int mf = 0; mf < 4; ++mf) {                                      \
            const int row = wm + mf * 16 + rA;                                \
            const int kc  = c ^ ((row >> 1) & 3);                             \
            a0[mf] = *(const bf16x8*)(&ldsbuf[BI][0][row * 32 + kc * 8]);     \
            a1[mf] = *(const bf16x8*)(&ldsbuf[BI][1][row * 32 + kc * 8]);     \
        }                                                                     \
        _Pragma("unroll")                                                     \
        for (int nf = 0; nf < 2; ++nf) {                                      \
            const int row = wn + nf * 16 + rA;                                \
            const int kc  = c ^ ((row >> 1) & 3);                             \
            b0[nf] = *(const bf16x8*)(&ldsbuf[BI][2][row * 32 + kc * 8]);     \
            b1[nf] = *(const bf16x8*)(&ldsbuf[BI][3][row * 32 + kc * 8]);     \
        }                                                                     \
        _Pragma("unroll")                                                     \
        for (int mf = 0; mf < 4; ++mf)                                        \
            _Pragma("unroll")                                                 \
            for (int nf = 0; nf < 2; ++nf) {                                  \
                acc[mf][nf] = __builtin_amdgcn_mfma_f32_16x16x32_bf16(        \
                    a0[mf], b0[nf], acc[mf][nf], 0, 0, 0);                    \
                acc[mf][nf] = __builtin_amdgcn_mfma_f32_16x16x32_bf16(        \
                    a0[mf], b1[nf], acc[mf][nf], 0, 0, 0);                    \
                acc[mf][nf] = __builtin_amdgcn_mfma_f32_16x16x32_bf16(        \
                    a1[mf], b0[nf], acc[mf][nf], 0, 0, 0);                    \
            }                                                                 \
    }

#define WAIT4 asm volatile("s_waitcnt vmcnt(4)" ::: "memory")
#define WAIT0 asm volatile("s_waitcnt vmcnt(0)" ::: "memory")
#define BARX   __builtin_amdgcn_s_barrier()
#define SCHED0 __builtin_amdgcn_sched_barrier(0)

// GEMM1+LIF phase (r11-proven 59.6us structure + htile XOR swizzle).
// Block = all 128 t x one b x 128 n-cols; counted-vmcnt 2-buffer pipeline.
#define GEMM_LIF_BODY(A0g, A1g, B0g, B1g, MM, COUNTER, LIST)                  \
    {                                                                         \
        const int tid  = threadIdx.x;                                         \
        const int wave = tid >> 6;                                            \
        const int lane = tid & 63;                                            \
        const int bid = blockIdx.x;                                           \
        const int pos = bid >> 3;                                             \
        const int bm  = (bid & 7) * 8 + (pos >> 3);                           \
        const int bn  = pos & 7;                                              \
        const int wm = (wave >> 2) * 64;                                      \
        const int wn = (wave & 3) * 32;                                       \
        f32x4 acc[4][2];                                                      \
        _Pragma("unroll")                                                     \
        for (int i = 0; i < 4; ++i)                                           \
            _Pragma("unroll")                                                 \
            for (int j = 0; j < 2; ++j) acc[i][j] = (f32x4){0.f,0.f,0.f,0.f}; \
        const int buf = wave >> 1;                                            \
        const unsigned short* gsrc =                                          \
            (buf == 0) ? (A0g) : (buf == 1) ? (A1g)                           \
                               : (buf == 2) ? (B0g) : (B1g);                  \
        const bool isA = (buf < 2);                                           \
        const int shalf = (wave & 1) * 256;                                   \
        STAGE(0, 0);                                                          \
        STAGE(1, 1);                                                          \
        for (int kt = 0; kt < 30; kt += 2) {                                  \
            WAIT4; BARX; SCHED0;                                              \
            COMPUTE(0);                                                       \
            BARX;                                                             \
            STAGE(0, kt + 2);                                                 \
            WAIT4; BARX; SCHED0;                                              \
            COMPUTE(1);                                                       \
            BARX;                                                             \
            STAGE(1, kt + 3);                                                 \
        }                                                                     \
        WAIT4; BARX; SCHED0;                                                  \
        COMPUTE(0);                                                           \
        BARX;                                                                 \
        WAIT0; BARX; SCHED0;                                                  \
        COMPUTE(1);                                                           \
        __syncthreads();                                                      \
        float* htile = (float*)&ldsbuf[0][0][0];                              \
        const int cr = lane >> 4, cc = lane & 15;                             \
        _Pragma("unroll")                                                     \
        for (int mf = 0; mf < 4; ++mf)                                        \
            _Pragma("unroll")                                                 \
            for (int nf = 0; nf < 2; ++nf)                                    \
                _Pragma("unroll")                                             \
                for (int r = 0; r < 4; ++r) {                                 \
                    const int t   = wm + mf * 16 + cr * 4 + r;                \
                    const int col = wn + nf * 16 + cc;                        \
                    htile[t * 128 + (col ^ ((t & 7) << 2))] = acc[mf][nf][r]; \
                }                                                             \
        __syncthreads();                                                      \
        if (tid < 128) {                                                      \
            const int col = tid;                                              \
            const int wv  = tid >> 6;                                         \
            double v = 0.0;                                                   \
            bool flagged = false;                                             \
            _Pragma("unroll 8")                                               \
            for (int t = 0; t < TT; ++t) {                                    \
                const float hcur = htile[t * 128 + (col ^ ((t & 7) << 2))];   \
                const double hv = v + ((double)hcur - v) * 0.5;               \
                const bool s = (hv >= 1.0);                                   \
                flagged = flagged || (fabs(hv - 1.0) < FLAG_THR);             \
                const unsigned long long bmask = __ballot(s);                 \
                if (lane == 0)                                                \
                    (MM)[(size_t)t * 1024 + bm * 16 + bn * 2 + wv] = bmask;   \
                v = s ? 0.0 : hv;                                             \
            }                                                                 \
            if (flagged) {                                                    \
                const int idx = atomicAdd((COUNTER), 1);                      \
                if (idx < MAX_FLAG) (LIST)[idx] = bm * 1024 + bn * 128 + col; \
            }                                                                 \
        }                                                                     \
    }

// Fixup phase: one 512-thr block per flagged column (grid-stride).
// Thread = (t, k-quarter); fp64 dot; 4-lane shfl reduce; thread-0 scan;
// 128-thread mask patch. Requires LDS double sv[128], uchar sp[128].
#define FIXUP_BODY(XP, W1P, MM, COUNTER, LIST)                                \
    {                                                                         \
        const int tid_ = threadIdx.x;                                         \
        int cnt_ = *(COUNTER); if (cnt_ > MAX_FLAG) cnt_ = MAX_FLAG;          \
        for (int ci = blockIdx.x; ci < cnt_; ci += gridDim.x) {               \
            const int e = (LIST)[ci];                                         \
            const int b = e >> 10, n = e & 1023;                              \
            const int t_ = tid_ >> 2, q_ = tid_ & 3;                          \
            const float4* xr =                                                \
                (const float4*)((XP) + (size_t)(t_ * 64 + b) * NN) + q_ * 64; \
            const float4* wr =                                                \
                (const float4*)((W1P) + (size_t)n * NN) + q_ * 64;            \
            double s = 0.0;                                                   \
            _Pragma("unroll 8")                                               \
            for (int j = 0; j < 64; ++j) {                                    \
                const float4 xv = xr[j];                                      \
                const float4 wv = wr[j];                                      \
                s = fma((double)xv.x, (double)wv.x, s);                       \
                s = fma((double)xv.y, (double)wv.y, s);                       \
                s = fma((double)xv.z, (double)wv.z, s);                       \
                s = fma((double)xv.w, (double)wv.w, s);                       \
            }                                                                 \
            s += __shfl_xor(s, 1);                                            \
            s += __shfl_xor(s, 2);                                            \
            if (q_ == 0) sv[t_] = s;                                          \
            __syncthreads();                                                  \
            if (tid_ == 0) {                                                  \
                double v = 0.0;                                               \
                _Pragma("unroll")                                             \
                for (int t = 0; t < TT; ++t) {                                \
                    const double hv = v + (sv[t] - v) * 0.5;                  \
                    const bool sf = (hv >= 1.0);                              \
                    sp[t] = sf;                                               \
                    v = sf ? 0.0 : hv;                                        \
                }                                                             \
            }                                                                 \
            __syncthreads();                                                  \
            if (tid_ < 128) {                                                 \
                const unsigned long long bit = 1ull << (e & 63);              \
                unsigned long long* mp =                                      \
                    &(MM)[(size_t)tid_ * 1024 + (e >> 6)];                    \
                if (sp[tid_]) atomicOr(mp, bit);                              \
                else          atomicAnd(mp, ~bit);                            \
            }                                                                 \
            __syncthreads();                                                  \
        }                                                                     \
    }

// spmm2 phase: 512-thr block handles 16 rows (two half-block rows at once).
// Requires LDS unsigned long long sm2[2][16].
#define SPMM2_BODY(MM, W2TP, OUTP)                                            \
    {                                                                         \
        const int tid_  = threadIdx.x;                                        \
        const int half_ = tid_ >> 8;                                          \
        const int ht_   = tid_ & 255;                                         \
        _Pragma("unroll")                                                     \
        for (int i = 0; i < 8; ++i) {                                         \
            const int r = blockIdx.x * 16 + i * 2 + half_;                    \
            if (ht_ < 16) sm2[half_][ht_] = (MM)[(size_t)r * 16 + ht_];       \
            __syncthreads();                                                  \
            double a0 = 0.0, a1 = 0.0, a2 = 0.0, a3 = 0.0;                    \
            for (int w = 0; w < 16; ++w) {                                    \
                unsigned long long bits = sm2[half_][w];                      \
                while (bits) {                                                \
                    const int l = __builtin_ctzll(bits);                      \
                    bits &= bits - 1;                                         \
                    const int n = w * 64 + l;                                 \
                    const float4 wv =                                         \
                        *(const float4*)&(W2TP)[(size_t)n * NN + ht_ * 4];    \
                    a0 += (double)wv.x; a1 += (double)wv.y;                   \
                    a2 += (double)wv.z; a3 += (double)wv.w;                   \
                }                                                             \
            }                                                                 \
            float4 o;                                                         \
            o.x = (float)a0; o.y = (float)a1;                                 \
            o.z = (float)a2; o.w = (float)a3;                                 \
            *(float4*)&(OUTP)[(size_t)r * NN + ht_ * 4] = o;                  \
            __syncthreads();                                                  \
        }                                                                     \
    }

// ---------------------------------------------------------------------------
// Cooperative mega kernel: gemm+lif -> grid.sync -> fixup -> grid.sync ->
// spmm2. Grid 512 x 512 thr, 2 blocks/CU (VGPR<=128, LDS 65.9KB).
// ---------------------------------------------------------------------------
__global__ __launch_bounds__(512, 4) void mega_k(
    const float* __restrict__ X, const float* __restrict__ W1,
    const unsigned short* __restrict__ A0g, const unsigned short* __restrict__ A1g,
    const unsigned short* __restrict__ B0g, const unsigned short* __restrict__ B1g,
    const float* __restrict__ W2T,
    unsigned long long* __restrict__ M, int* __restrict__ counter,
    int* __restrict__ list, float* __restrict__ OUT) {
    __shared__ unsigned short ldsbuf[2][4][128 * 32];
    __shared__ double sv[128];
    __shared__ unsigned char sp[128];
    __shared__ unsigned long long sm2[2][16];

    GEMM_LIF_BODY(A0g, A1g, B0g, B1g, M, counter, list);

    __threadfence();
    cg::this_grid().sync();

    FIXUP_BODY(X, W1, M, counter, list);

    __threadfence();
    cg::this_grid().sync();

    SPMM2_BODY(M, W2T, OUT);
}

// ---------------------------------------------------------------------------
// Fallback standalone kernels (used only if cooperative launch is rejected).
// ---------------------------------------------------------------------------
__global__ __launch_bounds__(512, 4) void gemm1_lif_k(
    const unsigned short* __restrict__ A0g, const unsigned short* __restrict__ A1g,
    const unsigned short* __restrict__ B0g, const unsigned short* __restrict__ B1g,
    unsigned long long* __restrict__ M, int* __restrict__ counter,
    int* __restrict__ list) {
    __shared__ unsigned short ldsbuf[2][4][128 * 32];
    GEMM_LIF_BODY(A0g, A1g, B0g, B1g, M, counter, list);
}

__global__ __launch_bounds__(512) void fixup_m_k(
    const float* __restrict__ X, const float* __restrict__ W1,
    unsigned long long* __restrict__ M, const int* __restrict__ counter,
    const int* __restrict__ list) {
    __shared__ double sv[128];
    __shared__ unsigned char sp[128];
    FIXUP_BODY(X, W1, M, counter, list);
}

__global__ __launch_bounds__(256) void spmm2_k(const unsigned long long* __restrict__ M,
                                               const float* __restrict__ W2T,
                                               float* __restrict__ OUT) {
    __shared__ unsigned long long sm[16];
    const int r   = blockIdx.x;
    const int tid = threadIdx.x;
    if (tid < 16) sm[tid] = M[(size_t)r * 16 + tid];
    __syncthreads();

    double a0 = 0.0, a1 = 0.0, a2 = 0.0, a3 = 0.0;
    for (int w = 0; w < 16; ++w) {
        unsigned long long bits = sm[w];
        while (bits) {
            const int l = __builtin_ctzll(bits);
            bits &= bits - 1;
            const int n = w * 64 + l;
            const float4 wv = *(const float4*)&W2T[(size_t)n * NN + tid * 4];
            a0 += (double)wv.x; a1 += (double)wv.y;
            a2 += (double)wv.z; a3 += (double)wv.w;
        }
    }
    float4 o;
    o.x = (float)a0; o.y = (float)a1; o.z = (float)a2; o.w = (float)a3;
    *(float4*)&OUT[(size_t)r * NN + tid * 4] = o;
}

// ---------------------------------------------------------------------------
// fp64 GEMM1 fallback path (round-3-proven) — only if ws too small.
// ---------------------------------------------------------------------------
#define KT 32
#define SA 132
#define SB 68
__global__ __launch_bounds__(256) void gemm1_f64(const float* __restrict__ X,
                                                 const float* __restrict__ W1,
                                                 float* __restrict__ H) {
    __shared__ float As[KT][SA];
    __shared__ float Bs[KT][SB];
    const int tid = threadIdx.x;
    const int bm  = blockIdx.y;
    const int bn  = blockIdx.x;
    const int tm  = tid >> 4;
    const int tn  = tid & 15;
    const int lrow = tid >> 3;
    const int lk4  = (tid & 7) << 2;
    double acc[8][4];
#pragma unroll
    for (int i = 0; i < 8; ++i)
#pragma unroll
        for (int j = 0; j < 4; ++j) acc[i][j] = 0.0;
    for (int kt = 0; kt < NN; kt += KT) {
#pragma unroll
        for (int p = 0; p < 4; ++p) {
            const int m = lrow + p * 32;
            const float4 v = *(const float4*)&X[(size_t)(bm * 128 + m) * NN + kt + lk4];
            As[lk4 + 0][m] = v.x; As[lk4 + 1][m] = v.y;
            As[lk4 + 2][m] = v.z; As[lk4 + 3][m] = v.w;
        }
#pragma unroll
        for (int p = 0; p < 2; ++p) {
            const int n = lrow + p * 32;
            const float4 v = *(const float4*)&W1[(size_t)(bn * 64 + n) * NN + kt + lk4];
            Bs[lk4 + 0][n] = v.x; Bs[lk4 + 1][n] = v.y;
            Bs[lk4 + 2][n] = v.z; Bs[lk4 + 3][n] = v.w;
        }
        __syncthreads();
#pragma unroll
        for (int k = 0; k < KT; ++k) {
            float a[8], b[4];
            *(float4*)&a[0] = *(const float4*)&As[k][tm * 8];
            *(float4*)&a[4] = *(const float4*)&As[k][tm * 8 + 4];
            *(float4*)&b[0] = *(const float4*)&Bs[k][tn * 4];
#pragma unroll
            for (int i = 0; i < 8; ++i)
#pragma unroll
                for (int j = 0; j < 4; ++j)
                    acc[i][j] = fma((double)a[i], (double)b[j], acc[i][j]);
        }
        __syncthreads();
    }
#pragma unroll
    for (int i = 0; i < 8; ++i) {
        float4 v;
        v.x = (float)acc[i][0]; v.y = (float)acc[i][1];
        v.z = (float)acc[i][2]; v.w = (float)acc[i][3];
        *(float4*)&H[(size_t)(bm * 128 + tm * 8 + i) * NN + bn * 64 + tn * 4] = v;
    }
}

__global__ __launch_bounds__(256) void transp_k(const float* __restrict__ A,
                                                float* __restrict__ B) {
    __shared__ float tile[32][33];
    const int tx  = threadIdx.x & 31;
    const int ty4 = (threadIdx.x >> 5) * 4;
    const int c0 = blockIdx.x * 32;
    const int r0 = blockIdx.y * 32;
#pragma unroll
    for (int i = 0; i < 4; ++i)
        tile[ty4 + i][tx] = A[(size_t)(r0 + ty4 + i) * NN + c0 + tx];
    __syncthreads();
#pragma unroll
    for (int i = 0; i < 4; ++i)
        B[(size_t)(c0 + ty4 + i) * NN + r0 + tx] = tile[tx][ty4 + i];
}

__global__ __launch_bounds__(256) void lif_k(const float* __restrict__ H,
                                             unsigned long long* __restrict__ M,
                                             int* __restrict__ counter,
                                             int* __restrict__ list) {
    const int e    = blockIdx.x * 256 + threadIdx.x;
    const int lane = threadIdx.x & 63;
    const int word = e >> 6;
    double v = 0.0;
    bool flagged = false;

    float buf[8];
#pragma unroll
    for (int i = 0; i < 8; ++i) buf[i] = H[(size_t)i * 65536 + e];

#pragma unroll 8
    for (int t = 0; t < TT; ++t) {
        const float hcur = buf[t & 7];
        if (t + 8 < TT) buf[t & 7] = H[(size_t)(t + 8) * 65536 + e];
        const double hv = v + ((double)hcur - v) * 0.5;
        const bool s = (hv >= 1.0);
        flagged = flagged || (fabs(hv - 1.0) < FLAG_THR);
        const unsigned long long bmask = __ballot(s);
        if (lane == 0) M[(size_t)t * 1024 + word] = bmask;
        v = s ? 0.0 : hv;
    }
    if (flagged) {
        const int idx = atomicAdd(counter, 1);
        if (idx < MAX_FLAG) list[idx] = e;
    }
}

// ---------------------------------------------------------------------------
extern "C" void kernel_launch(void* const* d_in, const int* in_sizes, int n_in,
                              void* d_out, int out_size, void* d_ws, size_t ws_size,
                              hipStream_t stream) {
    const float* x  = (const float*)d_in[0];
    const float* w1 = (const float*)d_in[1];
    const float* w2 = (const float*)d_in[2];
    float* out = (float*)d_out;
    char* ws = (char*)d_ws;

    const size_t oH = 0, oW2T = 33554432, oM = 37748736;
    const size_t oB0 = 38797312, oB1 = 40894464;
    const size_t oA0 = 42991616, oA1 = 59768832;
    const size_t oCnt = 76546048, oList = 76546304;
    const size_t needFull = 76808448;

    float* h   = (float*)(ws + oH);       // fp64-fallback only
    float* w2t = (float*)(ws + oW2T);
    unsigned long long* masks = (unsigned long long*)(ws + oM);

    if (ws_size >= needFull) {
        unsigned short* B0s = (unsigned short*)(ws + oB0);
        unsigned short* B1s = (unsigned short*)(ws + oB1);
        unsigned short* A0g = (unsigned short*)(ws + oA0);
        unsigned short* A1g = (unsigned short*)(ws + oA1);
        int* cnt  = (int*)(ws + oCnt);
        int* list = (int*)(ws + oList);

        split_k<<<10240, 256, 0, stream>>>(x, A0g, A1g, w1, B0s, B1s, w2, w2t, cnt);

        const float* Xa = x; const float* W1a = w1;
        const unsigned short* A0a = A0g; const unsigned short* A1a = A1g;
        const unsigned short* B0a = B0s; const unsigned short* B1a = B1s;
        const float* W2Ta = w2t;
        unsigned long long* Ma = masks;
        int* cntA = cnt; int* listA = list;
        float* outA = out;
        void* args[] = {(void*)&Xa, (void*)&W1a, (void*)&A0a, (void*)&A1a,
                        (void*)&B0a, (void*)&B1a, (void*)&W2Ta, (void*)&Ma,
                        (void*)&cntA, (void*)&listA, (void*)&outA};
        hipError_t ce = hipLaunchCooperativeKernel(
            reinterpret_cast<void*>(mega_k), dim3(512), dim3(512), args, 0, stream);
        if (ce != hipSuccess) {
            (void)hipGetLastError();  // clear error state
            gemm1_lif_k<<<512, 512, 0, stream>>>(A0g, A1g, B0s, B1s, masks, cnt, list);
            fixup_m_k<<<64, 512, 0, stream>>>(x, w1, masks, cnt, list);
            spmm2_k<<<8192, 256, 0, stream>>>(masks, w2t, out);
        }
    } else {
        // fallback: fp64 GEMM1 -> h exact -> no fixup needed
        int* cnt  = (int*)(ws + 38797312);
        int* list = (int*)(ws + 38797568);
        gemm1_f64<<<dim3(16, 64), 256, 0, stream>>>(x, w1, h);
        transp_k<<<dim3(32, 32), 256, 0, stream>>>(w2, w2t);
        hipMemsetAsync(cnt, 0, 4, stream);
        lif_k<<<256, 256, 0, stream>>>(h, masks, cnt, list);
        spmm2_k<<<8192, 256, 0, stream>>>(masks, w2t, out);
    }
}

// Round 14
// 121.750 us; speedup vs baseline: 3.1915x; 3.1915x over previous
//
#include <hip/hip_runtime.h>
#include <hip/hip_bf16.h>

#define TT 128
#define BB 64
#define NN 1024

typedef __attribute__((ext_vector_type(4))) float f32x4;
typedef __attribute__((ext_vector_type(8))) short bf16x8;

#define FLAG_THR 2e-4
#define MAX_FLAG 16384

// ---------------------------------------------------------------------------
// bf16 split helpers (RNE via bit trick; residual exact in fp32)
// ---------------------------------------------------------------------------
__device__ __forceinline__ unsigned short bf_hi_rne(float f, float& rem) {
    union { float f; unsigned int u; } c; c.f = f;
    const unsigned int r = c.u + 0x7fffu + ((c.u >> 16) & 1u);
    const unsigned short h = (unsigned short)(r >> 16);
    union { unsigned int u; float f; } b; b.u = ((unsigned int)h) << 16;
    rem = f - b.f;
    return h;
}

// Fused prep kernel (r11-proven), block-range dispatch:
//   [0,8192) split x; [8192,9216) split w1; [9216,10240) transpose w2.
//   block 0 thread 0 zeroes the flag counter.
__global__ __launch_bounds__(256) void split_k(const float* __restrict__ X,
                                               unsigned short* __restrict__ XHi,
                                               unsigned short* __restrict__ XLo,
                                               const float* __restrict__ W,
                                               unsigned short* __restrict__ WHi,
                                               unsigned short* __restrict__ WLo,
                                               const float* __restrict__ W2,
                                               float* __restrict__ W2T,
                                               int* __restrict__ cnt) {
    __shared__ float tile[32][33];
    if (blockIdx.x == 0 && threadIdx.x == 0) *cnt = 0;

    if (blockIdx.x >= 9216) {
        const int tblk = blockIdx.x - 9216;
        const int tx  = threadIdx.x & 31;
        const int ty4 = (threadIdx.x >> 5) * 4;
        const int c0 = (tblk & 31) * 32;
        const int r0 = (tblk >> 5) * 32;
#pragma unroll
        for (int i = 0; i < 4; ++i)
            tile[ty4 + i][tx] = W2[(size_t)(r0 + ty4 + i) * NN + c0 + tx];
        __syncthreads();
#pragma unroll
        for (int i = 0; i < 4; ++i)
            W2T[(size_t)(c0 + ty4 + i) * NN + r0 + tx] = tile[tx][ty4 + i];
        return;
    }

    const bool isX = blockIdx.x < 8192;
    const float* A = isX ? X : W;
    unsigned short* Hi = isX ? XHi : WHi;
    unsigned short* Lo = isX ? XLo : WLo;
    const size_t blk = isX ? blockIdx.x : (blockIdx.x - 8192);
    const size_t f = (blk * 256 + threadIdx.x) * 4;
    const float4 v = *(const float4*)(A + f);
    float r, r2;
    ushort4 hi, lo;
    hi.x = bf_hi_rne(v.x, r); lo.x = bf_hi_rne(r, r2);
    hi.y = bf_hi_rne(v.y, r); lo.y = bf_hi_rne(r, r2);
    hi.z = bf_hi_rne(v.z, r); lo.z = bf_hi_rne(r, r2);
    hi.w = bf_hi_rne(v.w, r); lo.w = bf_hi_rne(r, r2);
    *(ushort4*)(Hi + f) = hi;
    *(ushort4*)(Lo + f) = lo;
}

// ---------------------------------------------------------------------------
// GEMM1+LIF fused (r11-proven 59.6us structure + r12-proven htile swizzle).
// Block = all 128 t x one b x 128 n-cols; counted-vmcnt 2-buffer pipeline;
// conflict-free LDS swizzle; XCD-chunked block swizzle; wave-uniform
// global_load_lds dest.
// ---------------------------------------------------------------------------
#define STAGE(BI, KT)                                                         \
    {                                                                         \
        _Pragma("unroll")                                                     \
        for (int q = 0; q < 4; ++q) {                                         \
            const int slot = shalf + q * 64 + lane;                           \
            const int row  = slot >> 2;                                       \
            const int kc   = (slot & 3) ^ ((row >> 1) & 3);                   \
            const size_t grow = isA ? ((size_t)row * 64 + bm)                 \
                                    : ((size_t)bn * 128 + row);               \
            const unsigned short* gp =                                        \
                gsrc + grow * NN + (KT) * 32 + kc * 8;                        \
            __builtin_amdgcn_global_load_lds(                                 \
                (const __attribute__((address_space(1))) void*)gp,            \
                (__attribute__((address_space(3))) void*)(                    \
                    &ldsbuf[BI][buf][(wave & 1) * 2048 + q * 512]),           \
                16, 0, 0);                                                    \
        }                                                                     \
    }

#define COMPUTE(BI)                                                           \
    {                                                                         \
        const int c  = lane >> 4;                                             \
        const int rA = lane & 15;                                             \
        bf16x8 a0[4], a1[4], b0[2], b1[2];                                    \
        _Pragma("unroll")                                                     \
        for (int mf = 0; mf < 4; ++mf) {                                      \
            const int row = wm + mf * 16 + rA;                                \
            const int kc  = c ^ ((row >> 1) & 3);                             \
            a0[mf] = *(const bf16x8*)(&ldsbuf[BI][0][row * 32 + kc * 8]);     \
            a1[mf] = *(const bf16x8*)(&ldsbuf[BI][1][row * 32 + kc * 8]);     \
        }                                                                     \
        _Pragma("unroll")                                                     \
        for (int nf = 0; nf < 2; ++nf) {                                      \
            const int row = wn + nf * 16 + rA;                                \
            const int kc  = c ^ ((row >> 1) & 3);                             \
            b0[nf] = *(const bf16x8*)(&ldsbuf[BI][2][row * 32 + kc * 8]);     \
            b1[nf] = *(const bf16x8*)(&ldsbuf[BI][3][row * 32 + kc * 8]);     \
        }                                                                     \
        _Pragma("unroll")                                                     \
        for (int mf = 0; mf < 4; ++mf)                                        \
            _Pragma("unroll")                                                 \
            for (int nf = 0; nf < 2; ++nf) {                                  \
                acc[mf][nf] = __builtin_amdgcn_mfma_f32_16x16x32_bf16(        \
                    a0[mf], b0[nf], acc[mf][nf], 0, 0, 0);                    \
                acc[mf][nf] = __builtin_amdgcn_mfma_f32_16x16x32_bf16(        \
                    a0[mf], b1[nf], acc[mf][nf], 0, 0, 0);                    \
                acc[mf][nf] = __builtin_amdgcn_mfma_f32_16x16x32_bf16(        \
                    a1[mf], b0[nf], acc[mf][nf], 0, 0, 0);                    \
            }                                                                 \
    }

#define WAIT4 asm volatile("s_waitcnt vmcnt(4)" ::: "memory")
#define WAIT0 asm volatile("s_waitcnt vmcnt(0)" ::: "memory")
#define BARX   __builtin_amdgcn_s_barrier()
#define SCHED0 __builtin_amdgcn_sched_barrier(0)

__global__ __launch_bounds__(512, 4) void gemm1_lif_k(
    const unsigned short* __restrict__ A0g, const unsigned short* __restrict__ A1g,
    const unsigned short* __restrict__ B0g, const unsigned short* __restrict__ B1g,
    unsigned long long* __restrict__ M, int* __restrict__ counter,
    int* __restrict__ list) {
    __shared__ unsigned short ldsbuf[2][4][128 * 32];

    const int tid  = threadIdx.x;
    const int wave = tid >> 6;
    const int lane = tid & 63;
    const int bid = blockIdx.x;
    const int pos = bid >> 3;
    const int bm  = (bid & 7) * 8 + (pos >> 3);   // b value 0..63
    const int bn  = pos & 7;                      // n-block 0..7
    const int wm = (wave >> 2) * 64;
    const int wn = (wave & 3) * 32;

    f32x4 acc[4][2];
#pragma unroll
    for (int i = 0; i < 4; ++i)
#pragma unroll
        for (int j = 0; j < 2; ++j) acc[i][j] = (f32x4){0.f, 0.f, 0.f, 0.f};

    const int buf = wave >> 1;
    const unsigned short* gsrc =
        (buf == 0) ? A0g : (buf == 1) ? A1g : (buf == 2) ? B0g : B1g;
    const bool isA = (buf < 2);
    const int shalf = (wave & 1) * 256;

    STAGE(0, 0);
    STAGE(1, 1);

    for (int kt = 0; kt < 30; kt += 2) {
        WAIT4; BARX; SCHED0;
        COMPUTE(0);
        BARX;
        STAGE(0, kt + 2);
        WAIT4; BARX; SCHED0;
        COMPUTE(1);
        BARX;
        STAGE(1, kt + 3);
    }
    WAIT4; BARX; SCHED0;
    COMPUTE(0);
    BARX;
    WAIT0; BARX; SCHED0;
    COMPUTE(1);

    // ---- fused LIF epilogue (XOR-swizzled htile: conflict-free) ----
    __syncthreads();
    float* htile = (float*)&ldsbuf[0][0][0];  // 128 t x 128 col f32 = 64KB

    const int cr = lane >> 4, cc = lane & 15;
#pragma unroll
    for (int mf = 0; mf < 4; ++mf)
#pragma unroll
        for (int nf = 0; nf < 2; ++nf)
#pragma unroll
            for (int r = 0; r < 4; ++r) {
                const int t   = wm + mf * 16 + cr * 4 + r;
                const int col = wn + nf * 16 + cc;
                htile[t * 128 + (col ^ ((t & 7) << 2))] = acc[mf][nf][r];
            }
    __syncthreads();

    if (tid < 128) {  // waves 0,1 — full waves, ballot-safe
        const int col = tid;
        const int wv  = tid >> 6;
        double v = 0.0;
        bool flagged = false;
#pragma unroll 8
        for (int t = 0; t < TT; ++t) {
            const float hcur = htile[t * 128 + (col ^ ((t & 7) << 2))];
            const double hv = v + ((double)hcur - v) * 0.5;
            const bool s = (hv >= 1.0);
            flagged = flagged || (fabs(hv - 1.0) < FLAG_THR);
            const unsigned long long bmask = __ballot(s);
            if (lane == 0)
                M[(size_t)t * 1024 + bm * 16 + bn * 2 + wv] = bmask;
            v = s ? 0.0 : hv;
        }
        if (flagged) {
            const int idx = atomicAdd(counter, 1);
            if (idx < MAX_FLAG) list[idx] = bm * 1024 + bn * 128 + col;
        }
    }
}

// ---------------------------------------------------------------------------
// Merged fixup (r13-fallback-proven): one 512-thr block per flagged column
// (grid-stride). Thread = (t, k-quarter); fp64 dot; 4-lane shfl reduce;
// thread-0 scan; 128-thread mask patch.
// ---------------------------------------------------------------------------
__global__ __launch_bounds__(512) void fixup_m_k(
    const float* __restrict__ X, const float* __restrict__ W1,
    unsigned long long* __restrict__ M, const int* __restrict__ counter,
    const int* __restrict__ list) {
    __shared__ double sv[128];
    __shared__ unsigned char sp[128];
    const int tid_ = threadIdx.x;
    int cnt_ = *counter; if (cnt_ > MAX_FLAG) cnt_ = MAX_FLAG;

    for (int ci = blockIdx.x; ci < cnt_; ci += gridDim.x) {
        const int e = list[ci];
        const int b = e >> 10, n = e & 1023;
        const int t_ = tid_ >> 2, q_ = tid_ & 3;
        const float4* xr = (const float4*)(X + (size_t)(t_ * 64 + b) * NN) + q_ * 64;
        const float4* wr = (const float4*)(W1 + (size_t)n * NN) + q_ * 64;
        double s = 0.0;
#pragma unroll 8
        for (int j = 0; j < 64; ++j) {
            const float4 xv = xr[j];
            const float4 wv = wr[j];
            s = fma((double)xv.x, (double)wv.x, s);
            s = fma((double)xv.y, (double)wv.y, s);
            s = fma((double)xv.z, (double)wv.z, s);
            s = fma((double)xv.w, (double)wv.w, s);
        }
        s += __shfl_xor(s, 1);
        s += __shfl_xor(s, 2);
        if (q_ == 0) sv[t_] = s;
        __syncthreads();
        if (tid_ == 0) {
            double v = 0.0;
#pragma unroll
            for (int t = 0; t < TT; ++t) {
                const double hv = v + (sv[t] - v) * 0.5;
                const bool sf = (hv >= 1.0);
                sp[t] = sf;
                v = sf ? 0.0 : hv;
            }
        }
        __syncthreads();
        if (tid_ < 128) {
            const unsigned long long bit = 1ull << (e & 63);
            unsigned long long* mp = &M[(size_t)tid_ * 1024 + (e >> 6)];
            if (sp[tid_]) atomicOr(mp, bit);
            else          atomicAnd(mp, ~bit);
        }
        __syncthreads();
    }
}

// ---------------------------------------------------------------------------
// Sparse GEMM2 (r11-proven): out[r][:] = sum over active n of w2t[n][:].
// ---------------------------------------------------------------------------
__global__ __launch_bounds__(256) void spmm2_k(const unsigned long long* __restrict__ M,
                                               const float* __restrict__ W2T,
                                               float* __restrict__ OUT) {
    __shared__ unsigned long long sm[16];
    const int r   = blockIdx.x;
    const int tid = threadIdx.x;
    if (tid < 16) sm[tid] = M[(size_t)r * 16 + tid];
    __syncthreads();

    double a0 = 0.0, a1 = 0.0, a2 = 0.0, a3 = 0.0;
    for (int w = 0; w < 16; ++w) {
        unsigned long long bits = sm[w];
        while (bits) {
            const int l = __builtin_ctzll(bits);
            bits &= bits - 1;
            const int n = w * 64 + l;
            const float4 wv = *(const float4*)&W2T[(size_t)n * NN + tid * 4];
            a0 += (double)wv.x; a1 += (double)wv.y;
            a2 += (double)wv.z; a3 += (double)wv.w;
        }
    }
    float4 o;
    o.x = (float)a0; o.y = (float)a1; o.z = (float)a2; o.w = (float)a3;
    *(float4*)&OUT[(size_t)r * NN + tid * 4] = o;
}

// ---------------------------------------------------------------------------
// fp64 GEMM1 fallback path (round-3-proven) — only if ws too small.
// ---------------------------------------------------------------------------
#define KT 32
#define SA 132
#define SB 68
__global__ __launch_bounds__(256) void gemm1_f64(const float* __restrict__ X,
                                                 const float* __restrict__ W1,
                                                 float* __restrict__ H) {
    __shared__ float As[KT][SA];
    __shared__ float Bs[KT][SB];
    const int tid = threadIdx.x;
    const int bm  = blockIdx.y;
    const int bn  = blockIdx.x;
    const int tm  = tid >> 4;
    const int tn  = tid & 15;
    const int lrow = tid >> 3;
    const int lk4  = (tid & 7) << 2;
    double acc[8][4];
#pragma unroll
    for (int i = 0; i < 8; ++i)
#pragma unroll
        for (int j = 0; j < 4; ++j) acc[i][j] = 0.0;
    for (int kt = 0; kt < NN; kt += KT) {
#pragma unroll
        for (int p = 0; p < 4; ++p) {
            const int m = lrow + p * 32;
            const float4 v = *(const float4*)&X[(size_t)(bm * 128 + m) * NN + kt + lk4];
            As[lk4 + 0][m] = v.x; As[lk4 + 1][m] = v.y;
            As[lk4 + 2][m] = v.z; As[lk4 + 3][m] = v.w;
        }
#pragma unroll
        for (int p = 0; p < 2; ++p) {
            const int n = lrow + p * 32;
            const float4 v = *(const float4*)&W1[(size_t)(bn * 64 + n) * NN + kt + lk4];
            Bs[lk4 + 0][n] = v.x; Bs[lk4 + 1][n] = v.y;
            Bs[lk4 + 2][n] = v.z; Bs[lk4 + 3][n] = v.w;
        }
        __syncthreads();
#pragma unroll
        for (int k = 0; k < KT; ++k) {
            float a[8], b[4];
            *(float4*)&a[0] = *(const float4*)&As[k][tm * 8];
            *(float4*)&a[4] = *(const float4*)&As[k][tm * 8 + 4];
            *(float4*)&b[0] = *(const float4*)&Bs[k][tn * 4];
#pragma unroll
            for (int i = 0; i < 8; ++i)
#pragma unroll
                for (int j = 0; j < 4; ++j)
                    acc[i][j] = fma((double)a[i], (double)b[j], acc[i][j]);
        }
        __syncthreads();
    }
#pragma unroll
    for (int i = 0; i < 8; ++i) {
        float4 v;
        v.x = (float)acc[i][0]; v.y = (float)acc[i][1];
        v.z = (float)acc[i][2]; v.w = (float)acc[i][3];
        *(float4*)&H[(size_t)(bm * 128 + tm * 8 + i) * NN + bn * 64 + tn * 4] = v;
    }
}

__global__ __launch_bounds__(256) void transp_k(const float* __restrict__ A,
                                                float* __restrict__ B) {
    __shared__ float tile[32][33];
    const int tx  = threadIdx.x & 31;
    const int ty4 = (threadIdx.x >> 5) * 4;
    const int c0 = blockIdx.x * 32;
    const int r0 = blockIdx.y * 32;
#pragma unroll
    for (int i = 0; i < 4; ++i)
        tile[ty4 + i][tx] = A[(size_t)(r0 + ty4 + i) * NN + c0 + tx];
    __syncthreads();
#pragma unroll
    for (int i = 0; i < 4; ++i)
        B[(size_t)(c0 + ty4 + i) * NN + r0 + tx] = tile[tx][ty4 + i];
}

__global__ __launch_bounds__(256) void lif_k(const float* __restrict__ H,
                                             unsigned long long* __restrict__ M,
                                             int* __restrict__ counter,
                                             int* __restrict__ list) {
    const int e    = blockIdx.x * 256 + threadIdx.x;
    const int lane = threadIdx.x & 63;
    const int word = e >> 6;
    double v = 0.0;
    bool flagged = false;

    float buf[8];
#pragma unroll
    for (int i = 0; i < 8; ++i) buf[i] = H[(size_t)i * 65536 + e];

#pragma unroll 8
    for (int t = 0; t < TT; ++t) {
        const float hcur = buf[t & 7];
        if (t + 8 < TT) buf[t & 7] = H[(size_t)(t + 8) * 65536 + e];
        const double hv = v + ((double)hcur - v) * 0.5;
        const bool s = (hv >= 1.0);
        flagged = flagged || (fabs(hv - 1.0) < FLAG_THR);
        const unsigned long long bmask = __ballot(s);
        if (lane == 0) M[(size_t)t * 1024 + word] = bmask;
        v = s ? 0.0 : hv;
    }
    if (flagged) {
        const int idx = atomicAdd(counter, 1);
        if (idx < MAX_FLAG) list[idx] = e;
    }
}

// ---------------------------------------------------------------------------
extern "C" void kernel_launch(void* const* d_in, const int* in_sizes, int n_in,
                              void* d_out, int out_size, void* d_ws, size_t ws_size,
                              hipStream_t stream) {
    const float* x  = (const float*)d_in[0];
    const float* w1 = (const float*)d_in[1];
    const float* w2 = (const float*)d_in[2];
    float* out = (float*)d_out;
    char* ws = (char*)d_ws;

    const size_t oH = 0, oW2T = 33554432, oM = 37748736;
    const size_t oB0 = 38797312, oB1 = 40894464;
    const size_t oA0 = 42991616, oA1 = 59768832;
    const size_t oCnt = 76546048, oList = 76546304;
    const size_t needFull = 76808448;

    float* h   = (float*)(ws + oH);       // fp64-fallback only
    float* w2t = (float*)(ws + oW2T);
    unsigned long long* masks = (unsigned long long*)(ws + oM);

    if (ws_size >= needFull) {
        unsigned short* B0s = (unsigned short*)(ws + oB0);
        unsigned short* B1s = (unsigned short*)(ws + oB1);
        unsigned short* A0g = (unsigned short*)(ws + oA0);
        unsigned short* A1g = (unsigned short*)(ws + oA1);
        int* cnt  = (int*)(ws + oCnt);
        int* list = (int*)(ws + oList);

        split_k<<<10240, 256, 0, stream>>>(x, A0g, A1g, w1, B0s, B1s, w2, w2t, cnt);
        gemm1_lif_k<<<512, 512, 0, stream>>>(A0g, A1g, B0s, B1s, masks, cnt, list);
        fixup_m_k<<<64, 512, 0, stream>>>(x, w1, masks, cnt, list);
        spmm2_k<<<8192, 256, 0, stream>>>(masks, w2t, out);
    } else {
        // fallback: fp64 GEMM1 -> h exact -> no fixup needed
        int* cnt  = (int*)(ws + 38797312);
        int* list = (int*)(ws + 38797568);
        gemm1_f64<<<dim3(16, 64), 256, 0, stream>>>(x, w1, h);
        transp_k<<<dim3(32, 32), 256, 0, stream>>>(w2, w2t);
        hipMemsetAsync(cnt, 0, 4, stream);
        lif_k<<<256, 256, 0, stream>>>(h, masks, cnt, list);
        spmm2_k<<<8192, 256, 0, stream>>>(masks, w2t, out);
    }
}

// Round 15
// 98.830 us; speedup vs baseline: 3.9317x; 1.2319x over previous
//
#include <hip/hip_runtime.h>
#include <hip/hip_bf16.h>

#define TT 128
#define BB 64
#define NN 1024

typedef __attribute__((ext_vector_type(4))) float f32x4;
typedef __attribute__((ext_vector_type(8))) short bf16x8;

#define FLAG_THR 2e-4
#define MAX_FLAG 16384

// ---------------------------------------------------------------------------
// bf16 split helpers (RNE via bit trick; residual exact in fp32)
// ---------------------------------------------------------------------------
__device__ __forceinline__ unsigned short bf_hi_rne(float f, float& rem) {
    union { float f; unsigned int u; } c; c.f = f;
    const unsigned int r = c.u + 0x7fffu + ((c.u >> 16) & 1u);
    const unsigned short h = (unsigned short)(r >> 16);
    union { unsigned int u; float f; } b; b.u = ((unsigned int)h) << 16;
    rem = f - b.f;
    return h;
}

// Fused prep kernel (r11-proven, HBM-floor 13.3us), block-range dispatch:
//   [0,8192) split x; [8192,9216) split w1; [9216,10240) transpose w2.
//   block 0 thread 0 zeroes the flag counter.
__global__ __launch_bounds__(256) void split_k(const float* __restrict__ X,
                                               unsigned short* __restrict__ XHi,
                                               unsigned short* __restrict__ XLo,
                                               const float* __restrict__ W,
                                               unsigned short* __restrict__ WHi,
                                               unsigned short* __restrict__ WLo,
                                               const float* __restrict__ W2,
                                               float* __restrict__ W2T,
                                               int* __restrict__ cnt) {
    __shared__ float tile[32][33];
    if (blockIdx.x == 0 && threadIdx.x == 0) *cnt = 0;

    if (blockIdx.x >= 9216) {
        const int tblk = blockIdx.x - 9216;
        const int tx  = threadIdx.x & 31;
        const int ty4 = (threadIdx.x >> 5) * 4;
        const int c0 = (tblk & 31) * 32;
        const int r0 = (tblk >> 5) * 32;
#pragma unroll
        for (int i = 0; i < 4; ++i)
            tile[ty4 + i][tx] = W2[(size_t)(r0 + ty4 + i) * NN + c0 + tx];
        __syncthreads();
#pragma unroll
        for (int i = 0; i < 4; ++i)
            W2T[(size_t)(c0 + ty4 + i) * NN + r0 + tx] = tile[tx][ty4 + i];
        return;
    }

    const bool isX = blockIdx.x < 8192;
    const float* A = isX ? X : W;
    unsigned short* Hi = isX ? XHi : WHi;
    unsigned short* Lo = isX ? XLo : WLo;
    const size_t blk = isX ? blockIdx.x : (blockIdx.x - 8192);
    const size_t f = (blk * 256 + threadIdx.x) * 4;
    const float4 v = *(const float4*)(A + f);
    float r, r2;
    ushort4 hi, lo;
    hi.x = bf_hi_rne(v.x, r); lo.x = bf_hi_rne(r, r2);
    hi.y = bf_hi_rne(v.y, r); lo.y = bf_hi_rne(r, r2);
    hi.z = bf_hi_rne(v.z, r); lo.z = bf_hi_rne(r, r2);
    hi.w = bf_hi_rne(v.w, r); lo.w = bf_hi_rne(r, r2);
    *(ushort4*)(Hi + f) = hi;
    *(ushort4*)(Lo + f) = lo;
}

// ---------------------------------------------------------------------------
// GEMM1+LIF fused (r11/r14-proven 60us): block = all 128 t x one b x 128
// n-cols; counted-vmcnt 2-buffer pipeline; conflict-free LDS swizzle;
// XCD-chunked block swizzle; wave-uniform global_load_lds dest; XOR-swizzled
// htile epilogue (0 conflicts, r14-verified).
// ---------------------------------------------------------------------------
#define STAGE(BI, KT)                                                         \
    {                                                                         \
        _Pragma("unroll")                                                     \
        for (int q = 0; q < 4; ++q) {                                         \
            const int slot = shalf + q * 64 + lane;                           \
            const int row  = slot >> 2;                                       \
            const int kc   = (slot & 3) ^ ((row >> 1) & 3);                   \
            const size_t grow = isA ? ((size_t)row * 64 + bm)                 \
                                    : ((size_t)bn * 128 + row);               \
            const unsigned short* gp =                                        \
                gsrc + grow * NN + (KT) * 32 + kc * 8;                        \
            __builtin_amdgcn_global_load_lds(                                 \
                (const __attribute__((address_space(1))) void*)gp,            \
                (__attribute__((address_space(3))) void*)(                    \
                    &ldsbuf[BI][buf][(wave & 1) * 2048 + q * 512]),           \
                16, 0, 0);                                                    \
        }                                                                     \
    }

#define COMPUTE(BI)                                                           \
    {                                                                         \
        const int c  = lane >> 4;                                             \
        const int rA = lane & 15;                                             \
        bf16x8 a0[4], a1[4], b0[2], b1[2];                                    \
        _Pragma("unroll")                                                     \
        for (int mf = 0; mf < 4; ++mf) {                                      \
            const int row = wm + mf * 16 + rA;                                \
            const int kc  = c ^ ((row >> 1) & 3);                             \
            a0[mf] = *(const bf16x8*)(&ldsbuf[BI][0][row * 32 + kc * 8]);     \
            a1[mf] = *(const bf16x8*)(&ldsbuf[BI][1][row * 32 + kc * 8]);     \
        }                                                                     \
        _Pragma("unroll")                                                     \
        for (int nf = 0; nf < 2; ++nf) {                                      \
            const int row = wn + nf * 16 + rA;                                \
            const int kc  = c ^ ((row >> 1) & 3);                             \
            b0[nf] = *(const bf16x8*)(&ldsbuf[BI][2][row * 32 + kc * 8]);     \
            b1[nf] = *(const bf16x8*)(&ldsbuf[BI][3][row * 32 + kc * 8]);     \
        }                                                                     \
        _Pragma("unroll")                                                     \
        for (int mf = 0; mf < 4; ++mf)                                        \
            _Pragma("unroll")                                                 \
            for (int nf = 0; nf < 2; ++nf) {                                  \
                acc[mf][nf] = __builtin_amdgcn_mfma_f32_16x16x32_bf16(        \
                    a0[mf], b0[nf], acc[mf][nf], 0, 0, 0);                    \
                acc[mf][nf] = __builtin_amdgcn_mfma_f32_16x16x32_bf16(        \
                    a0[mf], b1[nf], acc[mf][nf], 0, 0, 0);                    \
                acc[mf][nf] = __builtin_amdgcn_mfma_f32_16x16x32_bf16(        \
                    a1[mf], b0[nf], acc[mf][nf], 0, 0, 0);                    \
            }                                                                 \
    }

#define WAIT4 asm volatile("s_waitcnt vmcnt(4)" ::: "memory")
#define WAIT0 asm volatile("s_waitcnt vmcnt(0)" ::: "memory")
#define BARX   __builtin_amdgcn_s_barrier()
#define SCHED0 __builtin_amdgcn_sched_barrier(0)

__global__ __launch_bounds__(512, 4) void gemm1_lif_k(
    const unsigned short* __restrict__ A0g, const unsigned short* __restrict__ A1g,
    const unsigned short* __restrict__ B0g, const unsigned short* __restrict__ B1g,
    unsigned long long* __restrict__ M, int* __restrict__ counter,
    int* __restrict__ list) {
    __shared__ unsigned short ldsbuf[2][4][128 * 32];

    const int tid  = threadIdx.x;
    const int wave = tid >> 6;
    const int lane = tid & 63;
    const int bid = blockIdx.x;
    const int pos = bid >> 3;
    const int bm  = (bid & 7) * 8 + (pos >> 3);   // b value 0..63
    const int bn  = pos & 7;                      // n-block 0..7
    const int wm = (wave >> 2) * 64;
    const int wn = (wave & 3) * 32;

    f32x4 acc[4][2];
#pragma unroll
    for (int i = 0; i < 4; ++i)
#pragma unroll
        for (int j = 0; j < 2; ++j) acc[i][j] = (f32x4){0.f, 0.f, 0.f, 0.f};

    const int buf = wave >> 1;
    const unsigned short* gsrc =
        (buf == 0) ? A0g : (buf == 1) ? A1g : (buf == 2) ? B0g : B1g;
    const bool isA = (buf < 2);
    const int shalf = (wave & 1) * 256;

    STAGE(0, 0);
    STAGE(1, 1);

    for (int kt = 0; kt < 30; kt += 2) {
        WAIT4; BARX; SCHED0;
        COMPUTE(0);
        BARX;
        STAGE(0, kt + 2);
        WAIT4; BARX; SCHED0;
        COMPUTE(1);
        BARX;
        STAGE(1, kt + 3);
    }
    WAIT4; BARX; SCHED0;
    COMPUTE(0);
    BARX;
    WAIT0; BARX; SCHED0;
    COMPUTE(1);

    // ---- fused LIF epilogue (XOR-swizzled htile: conflict-free) ----
    __syncthreads();
    float* htile = (float*)&ldsbuf[0][0][0];  // 128 t x 128 col f32 = 64KB

    const int cr = lane >> 4, cc = lane & 15;
#pragma unroll
    for (int mf = 0; mf < 4; ++mf)
#pragma unroll
        for (int nf = 0; nf < 2; ++nf)
#pragma unroll
            for (int r = 0; r < 4; ++r) {
                const int t   = wm + mf * 16 + cr * 4 + r;
                const int col = wn + nf * 16 + cc;
                htile[t * 128 + (col ^ ((t & 7) << 2))] = acc[mf][nf][r];
            }
    __syncthreads();

    if (tid < 128) {  // waves 0,1 — full waves, ballot-safe
        const int col = tid;
        const int wv  = tid >> 6;
        double v = 0.0;
        bool flagged = false;
#pragma unroll 8
        for (int t = 0; t < TT; ++t) {
            const float hcur = htile[t * 128 + (col ^ ((t & 7) << 2))];
            const double hv = v + ((double)hcur - v) * 0.5;
            const bool s = (hv >= 1.0);
            flagged = flagged || (fabs(hv - 1.0) < FLAG_THR);
            const unsigned long long bmask = __ballot(s);
            if (lane == 0)
                M[(size_t)t * 1024 + bm * 16 + bn * 2 + wv] = bmask;
            v = s ? 0.0 : hv;
        }
        if (flagged) {
            const int idx = atomicAdd(counter, 1);
            if (idx < MAX_FLAG) list[idx] = bm * 1024 + bn * 128 + col;
        }
    }
}

// ---------------------------------------------------------------------------
// Fixup phase A (r11-proven, ~4us): one wave per (flagged column, 8-t chunk)
// -> cnt*16 fine-grained work items over 1024 waves. Coalesced float4 loads.
// (r14's merged 64-block version was 35us: per-column serial streaming on one
// CU is memory-latency starved — keep the fine decomposition.)
// ---------------------------------------------------------------------------
__global__ __launch_bounds__(256) void fixup_dots_k(const float* __restrict__ X,
                                                    const float* __restrict__ W1,
                                                    const int* __restrict__ counter,
                                                    const int* __restrict__ list,
                                                    double* __restrict__ sbuf) {
    const int nw   = (gridDim.x * 256) >> 6;
    const int wid  = (blockIdx.x * 256 + threadIdx.x) >> 6;
    const int lane = threadIdx.x & 63;
    int cnt = *counter; if (cnt > MAX_FLAG) cnt = MAX_FLAG;
    const int total = cnt * 16;

    for (int item = wid; item < total; item += nw) {
        const int ci = item >> 4;
        const int tc = item & 15;
        const int e = list[ci];
        const int b = e >> 10, n = e & 1023;
        double wk[16];
        {
            const float4* wr = (const float4*)(W1 + (size_t)n * NN);
#pragma unroll
            for (int j = 0; j < 4; ++j) {
                const float4 wv = wr[lane + 64 * j];
                wk[4 * j + 0] = (double)wv.x; wk[4 * j + 1] = (double)wv.y;
                wk[4 * j + 2] = (double)wv.z; wk[4 * j + 3] = (double)wv.w;
            }
        }
#pragma unroll
        for (int tt = 0; tt < 8; ++tt) {
            const int t = tc * 8 + tt;
            const float4* xr = (const float4*)(X + (size_t)(t * 64 + b) * NN);
            double s = 0.0;
#pragma unroll
            for (int j = 0; j < 4; ++j) {
                const float4 xv = xr[lane + 64 * j];
                s = fma((double)xv.x, wk[4 * j + 0], s);
                s = fma((double)xv.y, wk[4 * j + 1], s);
                s = fma((double)xv.z, wk[4 * j + 2], s);
                s = fma((double)xv.w, wk[4 * j + 3], s);
            }
#pragma unroll
            for (int off = 32; off > 0; off >>= 1) s += __shfl_xor(s, off);
            if (lane == 0) sbuf[(size_t)ci * 128 + t] = s;
        }
    }
}

// ---------------------------------------------------------------------------
// Fixup phase B (r11-proven, ~2us): per-column LIF scan on exact dots +
// parallel mask patch.
// ---------------------------------------------------------------------------
__global__ __launch_bounds__(64) void fixup_scan_k(const double* __restrict__ sbuf,
                                                   const int* __restrict__ counter,
                                                   const int* __restrict__ list,
                                                   unsigned long long* __restrict__ M) {
    __shared__ double sv[128];
    __shared__ unsigned char sp[128];
    const int lane = threadIdx.x;
    int cnt = *counter; if (cnt > MAX_FLAG) cnt = MAX_FLAG;

    for (int ci = blockIdx.x; ci < cnt; ci += gridDim.x) {
        const int e = list[ci];
        sv[lane]      = sbuf[(size_t)ci * 128 + lane];
        sv[lane + 64] = sbuf[(size_t)ci * 128 + 64 + lane];
        __syncthreads();
        if (lane == 0) {
            double v = 0.0;
#pragma unroll
            for (int t = 0; t < TT; ++t) {
                const double hv = v + (sv[t] - v) * 0.5;
                const bool s = (hv >= 1.0);
                sp[t] = s;
                v = s ? 0.0 : hv;
            }
        }
        __syncthreads();
        const unsigned long long bit = 1ull << (e & 63);
        const size_t wbase = (size_t)(e >> 6);
#pragma unroll
        for (int p = 0; p < 2; ++p) {
            const int t = lane + p * 64;
            unsigned long long* mp = &M[(size_t)t * 1024 + wbase];
            if (sp[t]) atomicOr(mp, bit);
            else       atomicAnd(mp, ~bit);
        }
        __syncthreads();
    }
}

// ---------------------------------------------------------------------------
// Sparse GEMM2 (r11-proven, ~8.5us): out[r][:] = sum over active n of
// w2t[n][:]. fp64 acc; deterministic ascending-n order.
// ---------------------------------------------------------------------------
__global__ __launch_bounds__(256) void spmm2_k(const unsigned long long* __restrict__ M,
                                               const float* __restrict__ W2T,
                                               float* __restrict__ OUT) {
    __shared__ unsigned long long sm[16];
    const int r   = blockIdx.x;
    const int tid = threadIdx.x;
    if (tid < 16) sm[tid] = M[(size_t)r * 16 + tid];
    __syncthreads();

    double a0 = 0.0, a1 = 0.0, a2 = 0.0, a3 = 0.0;
    for (int w = 0; w < 16; ++w) {
        unsigned long long bits = sm[w];
        while (bits) {
            const int l = __builtin_ctzll(bits);
            bits &= bits - 1;
            const int n = w * 64 + l;
            const float4 wv = *(const float4*)&W2T[(size_t)n * NN + tid * 4];
            a0 += (double)wv.x; a1 += (double)wv.y;
            a2 += (double)wv.z; a3 += (double)wv.w;
        }
    }
    float4 o;
    o.x = (float)a0; o.y = (float)a1; o.z = (float)a2; o.w = (float)a3;
    *(float4*)&OUT[(size_t)r * NN + tid * 4] = o;
}

// ---------------------------------------------------------------------------
// fp64 GEMM1 fallback path (round-3-proven) — only if ws too small.
// ---------------------------------------------------------------------------
#define KT 32
#define SA 132
#define SB 68
__global__ __launch_bounds__(256) void gemm1_f64(const float* __restrict__ X,
                                                 const float* __restrict__ W1,
                                                 float* __restrict__ H) {
    __shared__ float As[KT][SA];
    __shared__ float Bs[KT][SB];
    const int tid = threadIdx.x;
    const int bm  = blockIdx.y;
    const int bn  = blockIdx.x;
    const int tm  = tid >> 4;
    const int tn  = tid & 15;
    const int lrow = tid >> 3;
    const int lk4  = (tid & 7) << 2;
    double acc[8][4];
#pragma unroll
    for (int i = 0; i < 8; ++i)
#pragma unroll
        for (int j = 0; j < 4; ++j) acc[i][j] = 0.0;
    for (int kt = 0; kt < NN; kt += KT) {
#pragma unroll
        for (int p = 0; p < 4; ++p) {
            const int m = lrow + p * 32;
            const float4 v = *(const float4*)&X[(size_t)(bm * 128 + m) * NN + kt + lk4];
            As[lk4 + 0][m] = v.x; As[lk4 + 1][m] = v.y;
            As[lk4 + 2][m] = v.z; As[lk4 + 3][m] = v.w;
        }
#pragma unroll
        for (int p = 0; p < 2; ++p) {
            const int n = lrow + p * 32;
            const float4 v = *(const float4*)&W1[(size_t)(bn * 64 + n) * NN + kt + lk4];
            Bs[lk4 + 0][n] = v.x; Bs[lk4 + 1][n] = v.y;
            Bs[lk4 + 2][n] = v.z; Bs[lk4 + 3][n] = v.w;
        }
        __syncthreads();
#pragma unroll
        for (int k = 0; k < KT; ++k) {
            float a[8], b[4];
            *(float4*)&a[0] = *(const float4*)&As[k][tm * 8];
            *(float4*)&a[4] = *(const float4*)&As[k][tm * 8 + 4];
            *(float4*)&b[0] = *(const float4*)&Bs[k][tn * 4];
#pragma unroll
            for (int i = 0; i < 8; ++i)
#pragma unroll
                for (int j = 0; j < 4; ++j)
                    acc[i][j] = fma((double)a[i], (double)b[j], acc[i][j]);
        }
        __syncthreads();
    }
#pragma unroll
    for (int i = 0; i < 8; ++i) {
        float4 v;
        v.x = (float)acc[i][0]; v.y = (float)acc[i][1];
        v.z = (float)acc[i][2]; v.w = (float)acc[i][3];
        *(float4*)&H[(size_t)(bm * 128 + tm * 8 + i) * NN + bn * 64 + tn * 4] = v;
    }
}

__global__ __launch_bounds__(256) void transp_k(const float* __restrict__ A,
                                                float* __restrict__ B) {
    __shared__ float tile[32][33];
    const int tx  = threadIdx.x & 31;
    const int ty4 = (threadIdx.x >> 5) * 4;
    const int c0 = blockIdx.x * 32;
    const int r0 = blockIdx.y * 32;
#pragma unroll
    for (int i = 0; i < 4; ++i)
        tile[ty4 + i][tx] = A[(size_t)(r0 + ty4 + i) * NN + c0 + tx];
    __syncthreads();
#pragma unroll
    for (int i = 0; i < 4; ++i)
        B[(size_t)(c0 + ty4 + i) * NN + r0 + tx] = tile[tx][ty4 + i];
}

__global__ __launch_bounds__(256) void lif_k(const float* __restrict__ H,
                                             unsigned long long* __restrict__ M,
                                             int* __restrict__ counter,
                                             int* __restrict__ list) {
    const int e    = blockIdx.x * 256 + threadIdx.x;
    const int lane = threadIdx.x & 63;
    const int word = e >> 6;
    double v = 0.0;
    bool flagged = false;

    float buf[8];
#pragma unroll
    for (int i = 0; i < 8; ++i) buf[i] = H[(size_t)i * 65536 + e];

#pragma unroll 8
    for (int t = 0; t < TT; ++t) {
        const float hcur = buf[t & 7];
        if (t + 8 < TT) buf[t & 7] = H[(size_t)(t + 8) * 65536 + e];
        const double hv = v + ((double)hcur - v) * 0.5;
        const bool s = (hv >= 1.0);
        flagged = flagged || (fabs(hv - 1.0) < FLAG_THR);
        const unsigned long long bmask = __ballot(s);
        if (lane == 0) M[(size_t)t * 1024 + word] = bmask;
        v = s ? 0.0 : hv;
    }
    if (flagged) {
        const int idx = atomicAdd(counter, 1);
        if (idx < MAX_FLAG) list[idx] = e;
    }
}

// ---------------------------------------------------------------------------
extern "C" void kernel_launch(void* const* d_in, const int* in_sizes, int n_in,
                              void* d_out, int out_size, void* d_ws, size_t ws_size,
                              hipStream_t stream) {
    const float* x  = (const float*)d_in[0];
    const float* w1 = (const float*)d_in[1];
    const float* w2 = (const float*)d_in[2];
    float* out = (float*)d_out;
    char* ws = (char*)d_ws;

    const size_t oH = 0, oW2T = 33554432, oM = 37748736;
    const size_t oB0 = 38797312, oB1 = 40894464;
    const size_t oA0 = 42991616, oA1 = 59768832;
    const size_t oCnt = 76546048, oList = 76546304;
    const size_t needFull = 76808448;

    float* h   = (float*)(ws + oH);       // fp64-fallback only
    float* w2t = (float*)(ws + oW2T);
    unsigned long long* masks = (unsigned long long*)(ws + oM);

    if (ws_size >= needFull) {
        unsigned short* B0s = (unsigned short*)(ws + oB0);
        unsigned short* B1s = (unsigned short*)(ws + oB1);
        unsigned short* A0g = (unsigned short*)(ws + oA0);
        unsigned short* A1g = (unsigned short*)(ws + oA1);
        int* cnt  = (int*)(ws + oCnt);
        int* list = (int*)(ws + oList);
        double* sbuf = (double*)(ws + oA0);  // overlays A0g (dead after gemm)

        split_k<<<10240, 256, 0, stream>>>(x, A0g, A1g, w1, B0s, B1s, w2, w2t, cnt);
        gemm1_lif_k<<<512, 512, 0, stream>>>(A0g, A1g, B0s, B1s, masks, cnt, list);
        fixup_dots_k<<<256, 256, 0, stream>>>(x, w1, cnt, list, sbuf);
        fixup_scan_k<<<256, 64, 0, stream>>>(sbuf, cnt, list, masks);
        spmm2_k<<<8192, 256, 0, stream>>>(masks, w2t, out);
    } else {
        // fallback: fp64 GEMM1 -> h exact -> no fixup needed
        int* cnt  = (int*)(ws + 38797312);
        int* list = (int*)(ws + 38797568);
        gemm1_f64<<<dim3(16, 64), 256, 0, stream>>>(x, w1, h);
        transp_k<<<dim3(32, 32), 256, 0, stream>>>(w2, w2t);
        hipMemsetAsync(cnt, 0, 4, stream);
        lif_k<<<256, 256, 0, stream>>>(h, masks, cnt, list);
        spmm2_k<<<8192, 256, 0, stream>>>(masks, w2t, out);
    }
}

// Round 16
// 98.711 us; speedup vs baseline: 3.9365x; 1.0012x over previous
//
#include <hip/hip_runtime.h>
#include <hip/hip_bf16.h>

#define TT 128
#define BB 64
#define NN 1024

typedef __attribute__((ext_vector_type(4))) float f32x4;
typedef __attribute__((ext_vector_type(8))) short bf16x8;

#define FLAG_THR 2e-4
#define MAX_FLAG 16384

// ---------------------------------------------------------------------------
// bf16 split helpers (RNE via bit trick; residual exact in fp32)
// ---------------------------------------------------------------------------
__device__ __forceinline__ unsigned short bf_hi_rne(float f, float& rem) {
    union { float f; unsigned int u; } c; c.f = f;
    const unsigned int r = c.u + 0x7fffu + ((c.u >> 16) & 1u);
    const unsigned short h = (unsigned short)(r >> 16);
    union { unsigned int u; float f; } b; b.u = ((unsigned int)h) << 16;
    rem = f - b.f;
    return h;
}

// Fused prep kernel (r11-proven, HBM-floor 13.3us), block-range dispatch:
//   [0,8192) split x; [8192,9216) split w1; [9216,10240) transpose w2.
//   block 0 thread 0 zeroes the flag counter.
__global__ __launch_bounds__(256) void split_k(const float* __restrict__ X,
                                               unsigned short* __restrict__ XHi,
                                               unsigned short* __restrict__ XLo,
                                               const float* __restrict__ W,
                                               unsigned short* __restrict__ WHi,
                                               unsigned short* __restrict__ WLo,
                                               const float* __restrict__ W2,
                                               float* __restrict__ W2T,
                                               int* __restrict__ cnt) {
    __shared__ float tile[32][33];
    if (blockIdx.x == 0 && threadIdx.x == 0) *cnt = 0;

    if (blockIdx.x >= 9216) {
        const int tblk = blockIdx.x - 9216;
        const int tx  = threadIdx.x & 31;
        const int ty4 = (threadIdx.x >> 5) * 4;
        const int c0 = (tblk & 31) * 32;
        const int r0 = (tblk >> 5) * 32;
#pragma unroll
        for (int i = 0; i < 4; ++i)
            tile[ty4 + i][tx] = W2[(size_t)(r0 + ty4 + i) * NN + c0 + tx];
        __syncthreads();
#pragma unroll
        for (int i = 0; i < 4; ++i)
            W2T[(size_t)(c0 + ty4 + i) * NN + r0 + tx] = tile[tx][ty4 + i];
        return;
    }

    const bool isX = blockIdx.x < 8192;
    const float* A = isX ? X : W;
    unsigned short* Hi = isX ? XHi : WHi;
    unsigned short* Lo = isX ? XLo : WLo;
    const size_t blk = isX ? blockIdx.x : (blockIdx.x - 8192);
    const size_t f = (blk * 256 + threadIdx.x) * 4;
    const float4 v = *(const float4*)(A + f);
    float r, r2;
    ushort4 hi, lo;
    hi.x = bf_hi_rne(v.x, r); lo.x = bf_hi_rne(r, r2);
    hi.y = bf_hi_rne(v.y, r); lo.y = bf_hi_rne(r, r2);
    hi.z = bf_hi_rne(v.z, r); lo.z = bf_hi_rne(r, r2);
    hi.w = bf_hi_rne(v.w, r); lo.w = bf_hi_rne(r, r2);
    *(ushort4*)(Hi + f) = hi;
    *(ushort4*)(Lo + f) = lo;
}

// ---------------------------------------------------------------------------
// GEMM1+LIF fused (r11/r14/r15-proven 60us): block = all 128 t x one b x 128
// n-cols; counted-vmcnt 2-buffer pipeline; conflict-free LDS swizzle;
// XCD-chunked block swizzle; wave-uniform global_load_lds dest; XOR-swizzled
// htile epilogue (0 conflicts, r14/r15-verified).
// ---------------------------------------------------------------------------
#define STAGE(BI, KT)                                                         \
    {                                                                         \
        _Pragma("unroll")                                                     \
        for (int q = 0; q < 4; ++q) {                                         \
            const int slot = shalf + q * 64 + lane;                           \
            const int row  = slot >> 2;                                       \
            const int kc   = (slot & 3) ^ ((row >> 1) & 3);                   \
            const size_t grow = isA ? ((size_t)row * 64 + bm)                 \
                                    : ((size_t)bn * 128 + row);               \
            const unsigned short* gp =                                        \
                gsrc + grow * NN + (KT) * 32 + kc * 8;                        \
            __builtin_amdgcn_global_load_lds(                                 \
                (const __attribute__((address_space(1))) void*)gp,            \
                (__attribute__((address_space(3))) void*)(                    \
                    &ldsbuf[BI][buf][(wave & 1) * 2048 + q * 512]),           \
                16, 0, 0);                                                    \
        }                                                                     \
    }

#define COMPUTE(BI)                                                           \
    {                                                                         \
        const int c  = lane >> 4;                                             \
        const int rA = lane & 15;                                             \
        bf16x8 a0[4], a1[4], b0[2], b1[2];                                    \
        _Pragma("unroll")                                                     \
        for (int mf = 0; mf < 4; ++mf) {                                      \
            const int row = wm + mf * 16 + rA;                                \
            const int kc  = c ^ ((row >> 1) & 3);                             \
            a0[mf] = *(const bf16x8*)(&ldsbuf[BI][0][row * 32 + kc * 8]);     \
            a1[mf] = *(const bf16x8*)(&ldsbuf[BI][1][row * 32 + kc * 8]);     \
        }                                                                     \
        _Pragma("unroll")                                                     \
        for (int nf = 0; nf < 2; ++nf) {                                      \
            const int row = wn + nf * 16 + rA;                                \
            const int kc  = c ^ ((row >> 1) & 3);                             \
            b0[nf] = *(const bf16x8*)(&ldsbuf[BI][2][row * 32 + kc * 8]);     \
            b1[nf] = *(const bf16x8*)(&ldsbuf[BI][3][row * 32 + kc * 8]);     \
        }                                                                     \
        _Pragma("unroll")                                                     \
        for (int mf = 0; mf < 4; ++mf)                                        \
            _Pragma("unroll")                                                 \
            for (int nf = 0; nf < 2; ++nf) {                                  \
                acc[mf][nf] = __builtin_amdgcn_mfma_f32_16x16x32_bf16(        \
                    a0[mf], b0[nf], acc[mf][nf], 0, 0, 0);                    \
                acc[mf][nf] = __builtin_amdgcn_mfma_f32_16x16x32_bf16(        \
                    a0[mf], b1[nf], acc[mf][nf], 0, 0, 0);                    \
                acc[mf][nf] = __builtin_amdgcn_mfma_f32_16x16x32_bf16(        \
                    a1[mf], b0[nf], acc[mf][nf], 0, 0, 0);                    \
            }                                                                 \
    }

#define WAIT4 asm volatile("s_waitcnt vmcnt(4)" ::: "memory")
#define WAIT0 asm volatile("s_waitcnt vmcnt(0)" ::: "memory")
#define BARX   __builtin_amdgcn_s_barrier()
#define SCHED0 __builtin_amdgcn_sched_barrier(0)

__global__ __launch_bounds__(512, 4) void gemm1_lif_k(
    const unsigned short* __restrict__ A0g, const unsigned short* __restrict__ A1g,
    const unsigned short* __restrict__ B0g, const unsigned short* __restrict__ B1g,
    unsigned long long* __restrict__ M, int* __restrict__ counter,
    int* __restrict__ list) {
    __shared__ unsigned short ldsbuf[2][4][128 * 32];

    const int tid  = threadIdx.x;
    const int wave = tid >> 6;
    const int lane = tid & 63;
    const int bid = blockIdx.x;
    const int pos = bid >> 3;
    const int bm  = (bid & 7) * 8 + (pos >> 3);   // b value 0..63
    const int bn  = pos & 7;                      // n-block 0..7
    const int wm = (wave >> 2) * 64;
    const int wn = (wave & 3) * 32;

    f32x4 acc[4][2];
#pragma unroll
    for (int i = 0; i < 4; ++i)
#pragma unroll
        for (int j = 0; j < 2; ++j) acc[i][j] = (f32x4){0.f, 0.f, 0.f, 0.f};

    const int buf = wave >> 1;
    const unsigned short* gsrc =
        (buf == 0) ? A0g : (buf == 1) ? A1g : (buf == 2) ? B0g : B1g;
    const bool isA = (buf < 2);
    const int shalf = (wave & 1) * 256;

    STAGE(0, 0);
    STAGE(1, 1);

    for (int kt = 0; kt < 30; kt += 2) {
        WAIT4; BARX; SCHED0;
        COMPUTE(0);
        BARX;
        STAGE(0, kt + 2);
        WAIT4; BARX; SCHED0;
        COMPUTE(1);
        BARX;
        STAGE(1, kt + 3);
    }
    WAIT4; BARX; SCHED0;
    COMPUTE(0);
    BARX;
    WAIT0; BARX; SCHED0;
    COMPUTE(1);

    // ---- fused LIF epilogue (XOR-swizzled htile: conflict-free) ----
    __syncthreads();
    float* htile = (float*)&ldsbuf[0][0][0];  // 128 t x 128 col f32 = 64KB

    const int cr = lane >> 4, cc = lane & 15;
#pragma unroll
    for (int mf = 0; mf < 4; ++mf)
#pragma unroll
        for (int nf = 0; nf < 2; ++nf)
#pragma unroll
            for (int r = 0; r < 4; ++r) {
                const int t   = wm + mf * 16 + cr * 4 + r;
                const int col = wn + nf * 16 + cc;
                htile[t * 128 + (col ^ ((t & 7) << 2))] = acc[mf][nf][r];
            }
    __syncthreads();

    if (tid < 128) {  // waves 0,1 — full waves, ballot-safe
        const int col = tid;
        const int wv  = tid >> 6;
        double v = 0.0;
        bool flagged = false;
#pragma unroll 8
        for (int t = 0; t < TT; ++t) {
            const float hcur = htile[t * 128 + (col ^ ((t & 7) << 2))];
            const double hv = v + ((double)hcur - v) * 0.5;
            const bool s = (hv >= 1.0);
            flagged = flagged || (fabs(hv - 1.0) < FLAG_THR);
            const unsigned long long bmask = __ballot(s);
            if (lane == 0)
                M[(size_t)t * 1024 + bm * 16 + bn * 2 + wv] = bmask;
            v = s ? 0.0 : hv;
        }
        if (flagged) {
            const int idx = atomicAdd(counter, 1);
            if (idx < MAX_FLAG) list[idx] = bm * 1024 + bn * 128 + col;
        }
    }
}

// ---------------------------------------------------------------------------
// Merged fixup, SINGLE kernel — preserves r11's proven work decomposition:
// 1024-thr block = 16 waves; wave w = one 8-t chunk of one flagged column,
// with r11's coalesced lane+64j float4 row reads (each load instr = one
// contiguous 1KB wave read). Dots -> LDS sv[] -> in-block thread-0 scan ->
// 128-thread parallel mask patch. (r14's failure was the ACCESS PATTERN
// change, not the merge itself — that version scattered 16B chunks across
// 128 rows per wave.)
// ---------------------------------------------------------------------------
__global__ __launch_bounds__(1024) void fixup_k(
    const float* __restrict__ X, const float* __restrict__ W1,
    unsigned long long* __restrict__ M, const int* __restrict__ counter,
    const int* __restrict__ list) {
    __shared__ double sv[128];
    __shared__ unsigned char sp[128];
    const int tid  = threadIdx.x;
    const int wave = tid >> 6;   // 0..15 -> t-chunk
    const int lane = tid & 63;
    int cnt = *counter; if (cnt > MAX_FLAG) cnt = MAX_FLAG;

    for (int ci = blockIdx.x; ci < cnt; ci += gridDim.x) {
        const int e = list[ci];
        const int b = e >> 10, n = e & 1023;

        double wk[16];
        {
            const float4* wr = (const float4*)(W1 + (size_t)n * NN);
#pragma unroll
            for (int j = 0; j < 4; ++j) {
                const float4 wv = wr[lane + 64 * j];
                wk[4 * j + 0] = (double)wv.x; wk[4 * j + 1] = (double)wv.y;
                wk[4 * j + 2] = (double)wv.z; wk[4 * j + 3] = (double)wv.w;
            }
        }
#pragma unroll
        for (int tt = 0; tt < 8; ++tt) {
            const int t = wave * 8 + tt;
            const float4* xr = (const float4*)(X + (size_t)(t * 64 + b) * NN);
            double s = 0.0;
#pragma unroll
            for (int j = 0; j < 4; ++j) {
                const float4 xv = xr[lane + 64 * j];
                s = fma((double)xv.x, wk[4 * j + 0], s);
                s = fma((double)xv.y, wk[4 * j + 1], s);
                s = fma((double)xv.z, wk[4 * j + 2], s);
                s = fma((double)xv.w, wk[4 * j + 3], s);
            }
#pragma unroll
            for (int off = 32; off > 0; off >>= 1) s += __shfl_xor(s, off);
            if (lane == 0) sv[t] = s;
        }
        __syncthreads();
        if (tid == 0) {
            double v = 0.0;
#pragma unroll
            for (int t = 0; t < TT; ++t) {
                const double hv = v + (sv[t] - v) * 0.5;
                const bool sf = (hv >= 1.0);
                sp[t] = sf;
                v = sf ? 0.0 : hv;
            }
        }
        __syncthreads();
        if (tid < 128) {
            // atomics stay: two flagged columns may share a mask word
            const unsigned long long bit = 1ull << (e & 63);
            unsigned long long* mp = &M[(size_t)tid * 1024 + (e >> 6)];
            if (sp[tid]) atomicOr(mp, bit);
            else         atomicAnd(mp, ~bit);
        }
        __syncthreads();  // sv/sp reused next ci iteration
    }
}

// ---------------------------------------------------------------------------
// Sparse GEMM2 (r11-proven, ~8.5us): out[r][:] = sum over active n of
// w2t[n][:]. fp64 acc; deterministic ascending-n order.
// ---------------------------------------------------------------------------
__global__ __launch_bounds__(256) void spmm2_k(const unsigned long long* __restrict__ M,
                                               const float* __restrict__ W2T,
                                               float* __restrict__ OUT) {
    __shared__ unsigned long long sm[16];
    const int r   = blockIdx.x;
    const int tid = threadIdx.x;
    if (tid < 16) sm[tid] = M[(size_t)r * 16 + tid];
    __syncthreads();

    double a0 = 0.0, a1 = 0.0, a2 = 0.0, a3 = 0.0;
    for (int w = 0; w < 16; ++w) {
        unsigned long long bits = sm[w];
        while (bits) {
            const int l = __builtin_ctzll(bits);
            bits &= bits - 1;
            const int n = w * 64 + l;
            const float4 wv = *(const float4*)&W2T[(size_t)n * NN + tid * 4];
            a0 += (double)wv.x; a1 += (double)wv.y;
            a2 += (double)wv.z; a3 += (double)wv.w;
        }
    }
    float4 o;
    o.x = (float)a0; o.y = (float)a1; o.z = (float)a2; o.w = (float)a3;
    *(float4*)&OUT[(size_t)r * NN + tid * 4] = o;
}

// ---------------------------------------------------------------------------
// fp64 GEMM1 fallback path (round-3-proven) — only if ws too small.
// ---------------------------------------------------------------------------
#define KT 32
#define SA 132
#define SB 68
__global__ __launch_bounds__(256) void gemm1_f64(const float* __restrict__ X,
                                                 const float* __restrict__ W1,
                                                 float* __restrict__ H) {
    __shared__ float As[KT][SA];
    __shared__ float Bs[KT][SB];
    const int tid = threadIdx.x;
    const int bm  = blockIdx.y;
    const int bn  = blockIdx.x;
    const int tm  = tid >> 4;
    const int tn  = tid & 15;
    const int lrow = tid >> 3;
    const int lk4  = (tid & 7) << 2;
    double acc[8][4];
#pragma unroll
    for (int i = 0; i < 8; ++i)
#pragma unroll
        for (int j = 0; j < 4; ++j) acc[i][j] = 0.0;
    for (int kt = 0; kt < NN; kt += KT) {
#pragma unroll
        for (int p = 0; p < 4; ++p) {
            const int m = lrow + p * 32;
            const float4 v = *(const float4*)&X[(size_t)(bm * 128 + m) * NN + kt + lk4];
            As[lk4 + 0][m] = v.x; As[lk4 + 1][m] = v.y;
            As[lk4 + 2][m] = v.z; As[lk4 + 3][m] = v.w;
        }
#pragma unroll
        for (int p = 0; p < 2; ++p) {
            const int n = lrow + p * 32;
            const float4 v = *(const float4*)&W1[(size_t)(bn * 64 + n) * NN + kt + lk4];
            Bs[lk4 + 0][n] = v.x; Bs[lk4 + 1][n] = v.y;
            Bs[lk4 + 2][n] = v.z; Bs[lk4 + 3][n] = v.w;
        }
        __syncthreads();
#pragma unroll
        for (int k = 0; k < KT; ++k) {
            float a[8], b[4];
            *(float4*)&a[0] = *(const float4*)&As[k][tm * 8];
            *(float4*)&a[4] = *(const float4*)&As[k][tm * 8 + 4];
            *(float4*)&b[0] = *(const float4*)&Bs[k][tn * 4];
#pragma unroll
            for (int i = 0; i < 8; ++i)
#pragma unroll
                for (int j = 0; j < 4; ++j)
                    acc[i][j] = fma((double)a[i], (double)b[j], acc[i][j]);
        }
        __syncthreads();
    }
#pragma unroll
    for (int i = 0; i < 8; ++i) {
        float4 v;
        v.x = (float)acc[i][0]; v.y = (float)acc[i][1];
        v.z = (float)acc[i][2]; v.w = (float)acc[i][3];
        *(float4*)&H[(size_t)(bm * 128 + tm * 8 + i) * NN + bn * 64 + tn * 4] = v;
    }
}

__global__ __launch_bounds__(256) void transp_k(const float* __restrict__ A,
                                                float* __restrict__ B) {
    __shared__ float tile[32][33];
    const int tx  = threadIdx.x & 31;
    const int ty4 = (threadIdx.x >> 5) * 4;
    const int c0 = blockIdx.x * 32;
    const int r0 = blockIdx.y * 32;
#pragma unroll
    for (int i = 0; i < 4; ++i)
        tile[ty4 + i][tx] = A[(size_t)(r0 + ty4 + i) * NN + c0 + tx];
    __syncthreads();
#pragma unroll
    for (int i = 0; i < 4; ++i)
        B[(size_t)(c0 + ty4 + i) * NN + r0 + tx] = tile[tx][ty4 + i];
}

__global__ __launch_bounds__(256) void lif_k(const float* __restrict__ H,
                                             unsigned long long* __restrict__ M,
                                             int* __restrict__ counter,
                                             int* __restrict__ list) {
    const int e    = blockIdx.x * 256 + threadIdx.x;
    const int lane = threadIdx.x & 63;
    const int word = e >> 6;
    double v = 0.0;
    bool flagged = false;

    float buf[8];
#pragma unroll
    for (int i = 0; i < 8; ++i) buf[i] = H[(size_t)i * 65536 + e];

#pragma unroll 8
    for (int t = 0; t < TT; ++t) {
        const float hcur = buf[t & 7];
        if (t + 8 < TT) buf[t & 7] = H[(size_t)(t + 8) * 65536 + e];
        const double hv = v + ((double)hcur - v) * 0.5;
        const bool s = (hv >= 1.0);
        flagged = flagged || (fabs(hv - 1.0) < FLAG_THR);
        const unsigned long long bmask = __ballot(s);
        if (lane == 0) M[(size_t)t * 1024 + word] = bmask;
        v = s ? 0.0 : hv;
    }
    if (flagged) {
        const int idx = atomicAdd(counter, 1);
        if (idx < MAX_FLAG) list[idx] = e;
    }
}

// ---------------------------------------------------------------------------
extern "C" void kernel_launch(void* const* d_in, const int* in_sizes, int n_in,
                              void* d_out, int out_size, void* d_ws, size_t ws_size,
                              hipStream_t stream) {
    const float* x  = (const float*)d_in[0];
    const float* w1 = (const float*)d_in[1];
    const float* w2 = (const float*)d_in[2];
    float* out = (float*)d_out;
    char* ws = (char*)d_ws;

    const size_t oH = 0, oW2T = 33554432, oM = 37748736;
    const size_t oB0 = 38797312, oB1 = 40894464;
    const size_t oA0 = 42991616, oA1 = 59768832;
    const size_t oCnt = 76546048, oList = 76546304;
    const size_t needFull = 76808448;

    float* h   = (float*)(ws + oH);       // fp64-fallback only
    float* w2t = (float*)(ws + oW2T);
    unsigned long long* masks = (unsigned long long*)(ws + oM);

    if (ws_size >= needFull) {
        unsigned short* B0s = (unsigned short*)(ws + oB0);
        unsigned short* B1s = (unsigned short*)(ws + oB1);
        unsigned short* A0g = (unsigned short*)(ws + oA0);
        unsigned short* A1g = (unsigned short*)(ws + oA1);
        int* cnt  = (int*)(ws + oCnt);
        int* list = (int*)(ws + oList);

        split_k<<<10240, 256, 0, stream>>>(x, A0g, A1g, w1, B0s, B1s, w2, w2t, cnt);
        gemm1_lif_k<<<512, 512, 0, stream>>>(A0g, A1g, B0s, B1s, masks, cnt, list);
        fixup_k<<<64, 1024, 0, stream>>>(x, w1, masks, cnt, list);
        spmm2_k<<<8192, 256, 0, stream>>>(masks, w2t, out);
    } else {
        // fallback: fp64 GEMM1 -> h exact -> no fixup needed
        int* cnt  = (int*)(ws + 38797312);
        int* list = (int*)(ws + 38797568);
        gemm1_f64<<<dim3(16, 64), 256, 0, stream>>>(x, w1, h);
        transp_k<<<dim3(32, 32), 256, 0, stream>>>(w2, w2t);
        hipMemsetAsync(cnt, 0, 4, stream);
        lif_k<<<256, 256, 0, stream>>>(h, masks, cnt, list);
        spmm2_k<<<8192, 256, 0, stream>>>(masks, w2t, out);
    }
}

// Round 17
// 95.227 us; speedup vs baseline: 4.0805x; 1.0366x over previous
//
#include <hip/hip_runtime.h>
#include <hip/hip_bf16.h>

#define TT 128
#define BB 64
#define NN 1024

typedef __attribute__((ext_vector_type(4))) float f32x4;
typedef __attribute__((ext_vector_type(8))) short bf16x8;

#define FLAG_THR 2e-4
#define MAX_FLAG 16384

// ---------------------------------------------------------------------------
// bf16 split helpers (RNE via bit trick; residual exact in fp32)
// ---------------------------------------------------------------------------
__device__ __forceinline__ unsigned short bf_hi_rne(float f, float& rem) {
    union { float f; unsigned int u; } c; c.f = f;
    const unsigned int r = c.u + 0x7fffu + ((c.u >> 16) & 1u);
    const unsigned short h = (unsigned short)(r >> 16);
    union { unsigned int u; float f; } b; b.u = ((unsigned int)h) << 16;
    rem = f - b.f;
    return h;
}

// Fused prep kernel (r11-proven, HBM-floor 13.3us), block-range dispatch:
//   [0,8192) split x; [8192,9216) split w1; [9216,10240) transpose w2.
//   block 0 thread 0 zeroes the flag counter.
__global__ __launch_bounds__(256) void split_k(const float* __restrict__ X,
                                               unsigned short* __restrict__ XHi,
                                               unsigned short* __restrict__ XLo,
                                               const float* __restrict__ W,
                                               unsigned short* __restrict__ WHi,
                                               unsigned short* __restrict__ WLo,
                                               const float* __restrict__ W2,
                                               float* __restrict__ W2T,
                                               int* __restrict__ cnt) {
    __shared__ float tile[32][33];
    if (blockIdx.x == 0 && threadIdx.x == 0) *cnt = 0;

    if (blockIdx.x >= 9216) {
        const int tblk = blockIdx.x - 9216;
        const int tx  = threadIdx.x & 31;
        const int ty4 = (threadIdx.x >> 5) * 4;
        const int c0 = (tblk & 31) * 32;
        const int r0 = (tblk >> 5) * 32;
#pragma unroll
        for (int i = 0; i < 4; ++i)
            tile[ty4 + i][tx] = W2[(size_t)(r0 + ty4 + i) * NN + c0 + tx];
        __syncthreads();
#pragma unroll
        for (int i = 0; i < 4; ++i)
            W2T[(size_t)(c0 + ty4 + i) * NN + r0 + tx] = tile[tx][ty4 + i];
        return;
    }

    const bool isX = blockIdx.x < 8192;
    const float* A = isX ? X : W;
    unsigned short* Hi = isX ? XHi : WHi;
    unsigned short* Lo = isX ? XLo : WLo;
    const size_t blk = isX ? blockIdx.x : (blockIdx.x - 8192);
    const size_t f = (blk * 256 + threadIdx.x) * 4;
    const float4 v = *(const float4*)(A + f);
    float r, r2;
    ushort4 hi, lo;
    hi.x = bf_hi_rne(v.x, r); lo.x = bf_hi_rne(r, r2);
    hi.y = bf_hi_rne(v.y, r); lo.y = bf_hi_rne(r, r2);
    hi.z = bf_hi_rne(v.z, r); lo.z = bf_hi_rne(r, r2);
    hi.w = bf_hi_rne(v.w, r); lo.w = bf_hi_rne(r, r2);
    *(ushort4*)(Hi + f) = hi;
    *(ushort4*)(Lo + f) = lo;
}

// ---------------------------------------------------------------------------
// GEMM1+LIF fused, round-17: 128t x 256n block tile, 8 waves (2m x 4n),
// 64x64 per wave (4x4 frags, 48 MFMA/step) -> LDS reads per FLOP cut 33%
// (16 ds_read_b128 : 48 MFMA vs 12:24), barriers per FLOP halved.
// Grid 256 = 1 block/CU. Counted-vmcnt 2-buffer pipeline (WAIT6: every wave
// stages exactly 6 x 16B via flat 48KB slot map; 64-slot issues never cross
// region boundaries since all region offsets are multiples of 64 slots).
// LDS: 2x48KB pipeline overlaid with 128KB htile (one 128KB block).
// Same proven swizzle involution, wave-uniform gload_lds dest, XCD-chunked
// block swizzle, XOR-swizzled htile epilogue.
// ---------------------------------------------------------------------------
#define WAIT6 asm volatile("s_waitcnt vmcnt(6)" ::: "memory")
#define WAIT0 asm volatile("s_waitcnt vmcnt(0)" ::: "memory")
#define BARX   __builtin_amdgcn_s_barrier()
#define SCHED0 __builtin_amdgcn_sched_barrier(0)

// Flat slot map (slot = 16B unit): [0,512)=A0, [512,1024)=A1,
// [1024,2048)=B0, [2048,3072)=B1. LDS ushort offset = slot*8.
#define STAGE(DST, KT)                                                        \
    {                                                                         \
        _Pragma("unroll")                                                     \
        for (int q = 0; q < 6; ++q) {                                         \
            const int slot0 = wave * 384 + q * 64;   /* wave-uniform */       \
            const int slot  = slot0 + lane;                                   \
            const int reg   = slot >> 9;             /* uniform per issue */  \
            const unsigned short* gsrc =                                      \
                (reg == 0) ? A0g : (reg == 1) ? A1g : (reg < 4) ? B0g : B1g;  \
            const int ls   = (reg < 2) ? (slot & 511) : (slot & 1023);        \
            const int row  = ls >> 2;                                         \
            const int kc   = (slot & 3) ^ ((row >> 1) & 3);                   \
            const size_t grow = (reg < 2) ? ((size_t)row * 64 + bm)           \
                                          : ((size_t)bn * 256 + row);         \
            const unsigned short* gp =                                        \
                gsrc + grow * NN + (KT) * 32 + kc * 8;                        \
            __builtin_amdgcn_global_load_lds(                                 \
                (const __attribute__((address_space(1))) void*)gp,            \
                (__attribute__((address_space(3))) void*)((DST) + slot0 * 8), \
                16, 0, 0);                                                    \
        }                                                                     \
    }

#define COMPUTE(SRC)                                                          \
    {                                                                         \
        const int c  = lane >> 4;                                             \
        const int rA = lane & 15;                                             \
        bf16x8 a0[4], a1[4], b0[4], b1[4];                                    \
        _Pragma("unroll")                                                     \
        for (int mf = 0; mf < 4; ++mf) {                                      \
            const int row = wm + mf * 16 + rA;                                \
            const int kc  = c ^ ((row >> 1) & 3);                             \
            a0[mf] = *(const bf16x8*)((SRC) + row * 32 + kc * 8);             \
            a1[mf] = *(const bf16x8*)((SRC) + 4096 + row * 32 + kc * 8);      \
        }                                                                     \
        _Pragma("unroll")                                                     \
        for (int nf = 0; nf < 4; ++nf) {                                      \
            const int row = wn + nf * 16 + rA;                                \
            const int kc  = c ^ ((row >> 1) & 3);                             \
            b0[nf] = *(const bf16x8*)((SRC) + 8192 + row * 32 + kc * 8);      \
            b1[nf] = *(const bf16x8*)((SRC) + 16384 + row * 32 + kc * 8);     \
        }                                                                     \
        _Pragma("unroll")                                                     \
        for (int mf = 0; mf < 4; ++mf)                                        \
            _Pragma("unroll")                                                 \
            for (int nf = 0; nf < 4; ++nf) {                                  \
                acc[mf][nf] = __builtin_amdgcn_mfma_f32_16x16x32_bf16(        \
                    a0[mf], b0[nf], acc[mf][nf], 0, 0, 0);                    \
                acc[mf][nf] = __builtin_amdgcn_mfma_f32_16x16x32_bf16(        \
                    a0[mf], b1[nf], acc[mf][nf], 0, 0, 0);                    \
                acc[mf][nf] = __builtin_amdgcn_mfma_f32_16x16x32_bf16(        \
                    a1[mf], b0[nf], acc[mf][nf], 0, 0, 0);                    \
            }                                                                 \
    }

__global__ __launch_bounds__(512, 2) void gemm1_lif_k(
    const unsigned short* __restrict__ A0g, const unsigned short* __restrict__ A1g,
    const unsigned short* __restrict__ B0g, const unsigned short* __restrict__ B1g,
    unsigned long long* __restrict__ M, int* __restrict__ counter,
    int* __restrict__ list) {
    __shared__ __align__(16) float smem[32768];  // 128KB: pipeline + htile
    unsigned short* lds0 = (unsigned short*)smem;            // 48KB
    unsigned short* lds1 = (unsigned short*)(smem + 12288);  // 48KB
    float* htile = smem;                                     // epilogue overlay

    const int tid  = threadIdx.x;
    const int wave = tid >> 6;        // 0..7
    const int lane = tid & 63;
    const int bid = blockIdx.x;       // 0..255
    const int pos = bid >> 3;         // 0..31
    const int bm  = (bid & 7) * 8 + (pos >> 2);   // b value 0..63
    const int bn  = pos & 3;                      // n-block 0..3 (x256)
    const int wm = (wave >> 2) * 64;  // t-range 0 / 64
    const int wn = (wave & 3) * 64;   // col 0 / 64 / 128 / 192

    f32x4 acc[4][4];
#pragma unroll
    for (int i = 0; i < 4; ++i)
#pragma unroll
        for (int j = 0; j < 4; ++j) acc[i][j] = (f32x4){0.f, 0.f, 0.f, 0.f};

    STAGE(lds0, 0);
    STAGE(lds1, 1);

    for (int kt = 0; kt < 30; kt += 2) {
        WAIT6; BARX; SCHED0;
        COMPUTE(lds0);
        BARX;
        STAGE(lds0, kt + 2);
        WAIT6; BARX; SCHED0;
        COMPUTE(lds1);
        BARX;
        STAGE(lds1, kt + 3);
    }
    WAIT6; BARX; SCHED0;
    COMPUTE(lds0);
    BARX;
    WAIT0; BARX; SCHED0;
    COMPUTE(lds1);

    // ---- fused LIF epilogue (XOR-swizzled htile 128t x 256col) ----
    __syncthreads();  // all waves done with LDS pipeline -> overlay htile

    const int cr = lane >> 4, cc = lane & 15;
#pragma unroll
    for (int mf = 0; mf < 4; ++mf)
#pragma unroll
        for (int nf = 0; nf < 4; ++nf)
#pragma unroll
            for (int r = 0; r < 4; ++r) {
                const int t   = wm + mf * 16 + cr * 4 + r;
                const int col = wn + nf * 16 + cc;
                htile[t * 256 + (col ^ ((t & 7) << 2))] = acc[mf][nf][r];
            }
    __syncthreads();

    if (tid < 256) {  // waves 0-3 — full waves, ballot-safe
        const int col = tid;
        const int wv  = tid >> 6;  // 0..3
        double v = 0.0;
        bool flagged = false;
#pragma unroll 8
        for (int t = 0; t < TT; ++t) {
            const float hcur = htile[t * 256 + (col ^ ((t & 7) << 2))];
            const double hv = v + ((double)hcur - v) * 0.5;
            const bool s = (hv >= 1.0);
            flagged = flagged || (fabs(hv - 1.0) < FLAG_THR);
            const unsigned long long bmask = __ballot(s);
            if (lane == 0)
                M[(size_t)t * 1024 + bm * 16 + bn * 4 + wv] = bmask;
            v = s ? 0.0 : hv;
        }
        if (flagged) {
            const int idx = atomicAdd(counter, 1);
            if (idx < MAX_FLAG) list[idx] = bm * 1024 + bn * 256 + col;
        }
    }
}

// ---------------------------------------------------------------------------
// Merged fixup (r16-proven): 1024-thr block = 16 waves; wave = one 8-t chunk
// with coalesced lane+64j float4 row reads; in-block scan + mask patch.
// ---------------------------------------------------------------------------
__global__ __launch_bounds__(1024) void fixup_k(
    const float* __restrict__ X, const float* __restrict__ W1,
    unsigned long long* __restrict__ M, const int* __restrict__ counter,
    const int* __restrict__ list) {
    __shared__ double sv[128];
    __shared__ unsigned char sp[128];
    const int tid  = threadIdx.x;
    const int wave = tid >> 6;   // 0..15 -> t-chunk
    const int lane = tid & 63;
    int cnt = *counter; if (cnt > MAX_FLAG) cnt = MAX_FLAG;

    for (int ci = blockIdx.x; ci < cnt; ci += gridDim.x) {
        const int e = list[ci];
        const int b = e >> 10, n = e & 1023;

        double wk[16];
        {
            const float4* wr = (const float4*)(W1 + (size_t)n * NN);
#pragma unroll
            for (int j = 0; j < 4; ++j) {
                const float4 wv = wr[lane + 64 * j];
                wk[4 * j + 0] = (double)wv.x; wk[4 * j + 1] = (double)wv.y;
                wk[4 * j + 2] = (double)wv.z; wk[4 * j + 3] = (double)wv.w;
            }
        }
#pragma unroll
        for (int tt = 0; tt < 8; ++tt) {
            const int t = wave * 8 + tt;
            const float4* xr = (const float4*)(X + (size_t)(t * 64 + b) * NN);
            double s = 0.0;
#pragma unroll
            for (int j = 0; j < 4; ++j) {
                const float4 xv = xr[lane + 64 * j];
                s = fma((double)xv.x, wk[4 * j + 0], s);
                s = fma((double)xv.y, wk[4 * j + 1], s);
                s = fma((double)xv.z, wk[4 * j + 2], s);
                s = fma((double)xv.w, wk[4 * j + 3], s);
            }
#pragma unroll
            for (int off = 32; off > 0; off >>= 1) s += __shfl_xor(s, off);
            if (lane == 0) sv[t] = s;
        }
        __syncthreads();
        if (tid == 0) {
            double v = 0.0;
#pragma unroll
            for (int t = 0; t < TT; ++t) {
                const double hv = v + (sv[t] - v) * 0.5;
                const bool sf = (hv >= 1.0);
                sp[t] = sf;
                v = sf ? 0.0 : hv;
            }
        }
        __syncthreads();
        if (tid < 128) {
            const unsigned long long bit = 1ull << (e & 63);
            unsigned long long* mp = &M[(size_t)tid * 1024 + (e >> 6)];
            if (sp[tid]) atomicOr(mp, bit);
            else         atomicAnd(mp, ~bit);
        }
        __syncthreads();
    }
}

// ---------------------------------------------------------------------------
// Sparse GEMM2 (r11-proven, ~8.5us): out[r][:] = sum over active n of
// w2t[n][:]. fp64 acc; deterministic ascending-n order.
// ---------------------------------------------------------------------------
__global__ __launch_bounds__(256) void spmm2_k(const unsigned long long* __restrict__ M,
                                               const float* __restrict__ W2T,
                                               float* __restrict__ OUT) {
    __shared__ unsigned long long sm[16];
    const int r   = blockIdx.x;
    const int tid = threadIdx.x;
    if (tid < 16) sm[tid] = M[(size_t)r * 16 + tid];
    __syncthreads();

    double a0 = 0.0, a1 = 0.0, a2 = 0.0, a3 = 0.0;
    for (int w = 0; w < 16; ++w) {
        unsigned long long bits = sm[w];
        while (bits) {
            const int l = __builtin_ctzll(bits);
            bits &= bits - 1;
            const int n = w * 64 + l;
            const float4 wv = *(const float4*)&W2T[(size_t)n * NN + tid * 4];
            a0 += (double)wv.x; a1 += (double)wv.y;
            a2 += (double)wv.z; a3 += (double)wv.w;
        }
    }
    float4 o;
    o.x = (float)a0; o.y = (float)a1; o.z = (float)a2; o.w = (float)a3;
    *(float4*)&OUT[(size_t)r * NN + tid * 4] = o;
}

// ---------------------------------------------------------------------------
// fp64 GEMM1 fallback path (round-3-proven) — only if ws too small.
// ---------------------------------------------------------------------------
#define KT 32
#define SA 132
#define SB 68
__global__ __launch_bounds__(256) void gemm1_f64(const float* __restrict__ X,
                                                 const float* __restrict__ W1,
                                                 float* __restrict__ H) {
    __shared__ float As[KT][SA];
    __shared__ float Bs[KT][SB];
    const int tid = threadIdx.x;
    const int bm  = blockIdx.y;
    const int bn  = blockIdx.x;
    const int tm  = tid >> 4;
    const int tn  = tid & 15;
    const int lrow = tid >> 3;
    const int lk4  = (tid & 7) << 2;
    double acc[8][4];
#pragma unroll
    for (int i = 0; i < 8; ++i)
#pragma unroll
        for (int j = 0; j < 4; ++j) acc[i][j] = 0.0;
    for (int kt = 0; kt < NN; kt += KT) {
#pragma unroll
        for (int p = 0; p < 4; ++p) {
            const int m = lrow + p * 32;
            const float4 v = *(const float4*)&X[(size_t)(bm * 128 + m) * NN + kt + lk4];
            As[lk4 + 0][m] = v.x; As[lk4 + 1][m] = v.y;
            As[lk4 + 2][m] = v.z; As[lk4 + 3][m] = v.w;
        }
#pragma unroll
        for (int p = 0; p < 2; ++p) {
            const int n = lrow + p * 32;
            const float4 v = *(const float4*)&W1[(size_t)(bn * 64 + n) * NN + kt + lk4];
            Bs[lk4 + 0][n] = v.x; Bs[lk4 + 1][n] = v.y;
            Bs[lk4 + 2][n] = v.z; Bs[lk4 + 3][n] = v.w;
        }
        __syncthreads();
#pragma unroll
        for (int k = 0; k < KT; ++k) {
            float a[8], b[4];
            *(float4*)&a[0] = *(const float4*)&As[k][tm * 8];
            *(float4*)&a[4] = *(const float4*)&As[k][tm * 8 + 4];
            *(float4*)&b[0] = *(const float4*)&Bs[k][tn * 4];
#pragma unroll
            for (int i = 0; i < 8; ++i)
#pragma unroll
                for (int j = 0; j < 4; ++j)
                    acc[i][j] = fma((double)a[i], (double)b[j], acc[i][j]);
        }
        __syncthreads();
    }
#pragma unroll
    for (int i = 0; i < 8; ++i) {
        float4 v;
        v.x = (float)acc[i][0]; v.y = (float)acc[i][1];
        v.z = (float)acc[i][2]; v.w = (float)acc[i][3];
        *(float4*)&H[(size_t)(bm * 128 + tm * 8 + i) * NN + bn * 64 + tn * 4] = v;
    }
}

__global__ __launch_bounds__(256) void transp_k(const float* __restrict__ A,
                                                float* __restrict__ B) {
    __shared__ float tile[32][33];
    const int tx  = threadIdx.x & 31;
    const int ty4 = (threadIdx.x >> 5) * 4;
    const int c0 = blockIdx.x * 32;
    const int r0 = blockIdx.y * 32;
#pragma unroll
    for (int i = 0; i < 4; ++i)
        tile[ty4 + i][tx] = A[(size_t)(r0 + ty4 + i) * NN + c0 + tx];
    __syncthreads();
#pragma unroll
    for (int i = 0; i < 4; ++i)
        B[(size_t)(c0 + ty4 + i) * NN + r0 + tx] = tile[tx][ty4 + i];
}

__global__ __launch_bounds__(256) void lif_k(const float* __restrict__ H,
                                             unsigned long long* __restrict__ M,
                                             int* __restrict__ counter,
                                             int* __restrict__ list) {
    const int e    = blockIdx.x * 256 + threadIdx.x;
    const int lane = threadIdx.x & 63;
    const int word = e >> 6;
    double v = 0.0;
    bool flagged = false;

    float buf[8];
#pragma unroll
    for (int i = 0; i < 8; ++i) buf[i] = H[(size_t)i * 65536 + e];

#pragma unroll 8
    for (int t = 0; t < TT; ++t) {
        const float hcur = buf[t & 7];
        if (t + 8 < TT) buf[t & 7] = H[(size_t)(t + 8) * 65536 + e];
        const double hv = v + ((double)hcur - v) * 0.5;
        const bool s = (hv >= 1.0);
        flagged = flagged || (fabs(hv - 1.0) < FLAG_THR);
        const unsigned long long bmask = __ballot(s);
        if (lane == 0) M[(size_t)t * 1024 + word] = bmask;
        v = s ? 0.0 : hv;
    }
    if (flagged) {
        const int idx = atomicAdd(counter, 1);
        if (idx < MAX_FLAG) list[idx] = e;
    }
}

// ---------------------------------------------------------------------------
extern "C" void kernel_launch(void* const* d_in, const int* in_sizes, int n_in,
                              void* d_out, int out_size, void* d_ws, size_t ws_size,
                              hipStream_t stream) {
    const float* x  = (const float*)d_in[0];
    const float* w1 = (const float*)d_in[1];
    const float* w2 = (const float*)d_in[2];
    float* out = (float*)d_out;
    char* ws = (char*)d_ws;

    const size_t oH = 0, oW2T = 33554432, oM = 37748736;
    const size_t oB0 = 38797312, oB1 = 40894464;
    const size_t oA0 = 42991616, oA1 = 59768832;
    const size_t oCnt = 76546048, oList = 76546304;
    const size_t needFull = 76808448;

    float* h   = (float*)(ws + oH);       // fp64-fallback only
    float* w2t = (float*)(ws + oW2T);
    unsigned long long* masks = (unsigned long long*)(ws + oM);

    if (ws_size >= needFull) {
        unsigned short* B0s = (unsigned short*)(ws + oB0);
        unsigned short* B1s = (unsigned short*)(ws + oB1);
        unsigned short* A0g = (unsigned short*)(ws + oA0);
        unsigned short* A1g = (unsigned short*)(ws + oA1);
        int* cnt  = (int*)(ws + oCnt);
        int* list = (int*)(ws + oList);

        split_k<<<10240, 256, 0, stream>>>(x, A0g, A1g, w1, B0s, B1s, w2, w2t, cnt);
        gemm1_lif_k<<<256, 512, 0, stream>>>(A0g, A1g, B0s, B1s, masks, cnt, list);
        fixup_k<<<64, 1024, 0, stream>>>(x, w1, masks, cnt, list);
        spmm2_k<<<8192, 256, 0, stream>>>(masks, w2t, out);
    } else {
        // fallback: fp64 GEMM1 -> h exact -> no fixup needed
        int* cnt  = (int*)(ws + 38797312);
        int* list = (int*)(ws + 38797568);
        gemm1_f64<<<dim3(16, 64), 256, 0, stream>>>(x, w1, h);
        transp_k<<<dim3(32, 32), 256, 0, stream>>>(w2, w2t);
        hipMemsetAsync(cnt, 0, 4, stream);
        lif_k<<<256, 256, 0, stream>>>(h, masks, cnt, list);
        spmm2_k<<<8192, 256, 0, stream>>>(masks, w2t, out);
    }
}